// Round 7
// baseline (108.992 us; speedup 1.0000x reference)
//
#include <hip/hip_runtime.h>
#include <hip/hip_fp16.h>
#include <math.h>

#define N_ATOMS 21
#define DESC 210
#define APAD 224            // padded descriptor length (7 x 32)
#define T_ROWS 12000
#define TPAD 12032
#define BATCH 64
#define NBLK_A 376          // gemmA blocks: 32 t each, 376*32 = 12032
#define NCH_C 256           // k_C t-chunks
#define TC_C 47             // 256*47 = 12032 >= 12000

#define QCONST 0.22360679774997896f   // sqrt(5)/10
#define K0CONST (1.0f/60.0f)          // 5/(3*sig^2)

typedef short bf16x8 __attribute__((ext_vector_type(8)));
typedef float f32x4 __attribute__((ext_vector_type(4)));

__device__ __forceinline__ float u2f(unsigned int u) {
    union { unsigned int u; float f; } x; x.u = u; return x.f;
}
__device__ __forceinline__ unsigned short f2bf(float f) {
    union { float f; unsigned int u; } x; x.f = f;
    unsigned int r = x.u + 0x7fffu + ((x.u >> 16) & 1u);  // RNE
    return (unsigned short)(r >> 16);
}
__device__ __forceinline__ float bf2f(unsigned short h) {
    return u2f((unsigned int)h << 16);
}

// ---------------- k_prep: Abf[m][224] = bf16(q/dist), na2 = ||bf16 row||^2 ----------------
__global__ __launch_bounds__(256) void k_prep(const float* __restrict__ Rs,
                                              unsigned short* __restrict__ Abf,
                                              float* __restrict__ na2) {
    int m = blockIdx.x;
    __shared__ float R[N_ATOMS * 3];
    __shared__ float red[256];
    int tid = threadIdx.x;
    if (tid < N_ATOMS * 3) R[tid] = Rs[m * N_ATOMS * 3 + tid];
    __syncthreads();
    float val = 0.f;
    if (tid < DESC) {
        int p = tid;
        int i = (int)((1.0f + sqrtf(1.0f + 8.0f * (float)p)) * 0.5f);
        while (i * (i - 1) / 2 > p) --i;
        while ((i + 1) * i / 2 <= p) ++i;
        int j = p - i * (i - 1) / 2;
        float dx = R[i * 3 + 0] - R[j * 3 + 0];
        float dy = R[i * 3 + 1] - R[j * 3 + 1];
        float dz = R[i * 3 + 2] - R[j * 3 + 2];
        float d = sqrtf(dx * dx + dy * dy + dz * dz);
        val = QCONST / d;
    }
    unsigned short h = f2bf(val);
    if (tid < APAD) Abf[m * APAD + tid] = h;
    float va = bf2f(h);
    red[tid] = va * va;
    __syncthreads();
    for (int s = 128; s > 0; s >>= 1) {
        if (tid < s) red[tid] += red[tid + s];
        __syncthreads();
    }
    if (tid == 0) na2[m] = red[0];
}

// ---------------- k_gemmA: P=A.B^T, Q=A.J^T via MFMA; epilogue -> w1q/w2/es/rs ----------------
// 376 blocks x 256 thr (4 waves). Wave w = m-tile (16 molecules). Block = 32 t.
// Frag layouts (mfma_f32_16x16x32_bf16): A/B: row|col = lane&15, k = (lane>>4)*8+e.
// C/D: col = lane&15 (t), row = (lane>>4)*4+reg (m).  [m89-verified C/D]
__global__ __launch_bounds__(256, 4) void k_gemmA(const float* __restrict__ Btr,
                                                  const float* __restrict__ Jx,
                                                  const unsigned short* __restrict__ Abf,
                                                  const float* __restrict__ na2,
                                                  float* __restrict__ w12,   // [TPAD][128]
                                                  float* __restrict__ es_p,  // [NBLK_A][64]
                                                  float* __restrict__ rs_p) {
    const int blk = blockIdx.x;
    const int t0 = blk * 32;
    const int tid = threadIdx.x;
    const int l = tid & 63;
    const int w = __builtin_amdgcn_readfirstlane(tid >> 6);  // m-tile 0..3
    const int lr = l & 15;
    const int kb = l >> 4;

    f32x4 accP0 = {0.f, 0.f, 0.f, 0.f}, accQ0 = {0.f, 0.f, 0.f, 0.f};
    f32x4 accP1 = {0.f, 0.f, 0.f, 0.f}, accQ1 = {0.f, 0.f, 0.f, 0.f};
    float nb0 = 0.f, nb1 = 0.f, bj0 = 0.f, bj1 = 0.f;

    int tA = t0 + lr;       if (tA > T_ROWS - 1) tA = T_ROWS - 1;
    int tB = t0 + 16 + lr;  if (tB > T_ROWS - 1) tB = T_ROWS - 1;
    const size_t rb0 = (size_t)tA * DESC;
    const size_t rb1 = (size_t)tB * DESC;
    const int am = (w * 16 + lr) * APAD;

#pragma unroll
    for (int k8 = 0; k8 < 7; ++k8) {
        const int d0 = k8 * 32 + kb * 8;
        union { uint4 u; bf16x8 h; } au;
        au.u = *(const uint4*)(Abf + am + d0);  // 8 bf16, 16B aligned
        float vb0[8], vj0[8], vb1[8], vj1[8];
        if (k8 < 6) {
#pragma unroll
            for (int e = 0; e < 8; e += 2) {
                float2 x = *(const float2*)(Btr + rb0 + d0 + e); vb0[e] = x.x; vb0[e + 1] = x.y;
                float2 y = *(const float2*)(Jx  + rb0 + d0 + e); vj0[e] = y.x; vj0[e + 1] = y.y;
                float2 z = *(const float2*)(Btr + rb1 + d0 + e); vb1[e] = z.x; vb1[e + 1] = z.y;
                float2 u = *(const float2*)(Jx  + rb1 + d0 + e); vj1[e] = u.x; vj1[e + 1] = u.y;
            }
        } else {  // tail k-step: mask d >= 210
#pragma unroll
            for (int e = 0; e < 8; e++) {
                bool ok = (d0 + e) < DESC;
                vb0[e] = ok ? Btr[rb0 + d0 + e] : 0.f;
                vj0[e] = ok ? Jx [rb0 + d0 + e] : 0.f;
                vb1[e] = ok ? Btr[rb1 + d0 + e] : 0.f;
                vj1[e] = ok ? Jx [rb1 + d0 + e] : 0.f;
            }
        }
        bf16x8 b0f, j0f, b1f, j1f;
#pragma unroll
        for (int e = 0; e < 8; e++) {
            unsigned short hb0 = f2bf(vb0[e]), hj0 = f2bf(vj0[e]);
            unsigned short hb1 = f2bf(vb1[e]), hj1 = f2bf(vj1[e]);
            b0f[e] = (short)hb0; j0f[e] = (short)hj0;
            b1f[e] = (short)hb1; j1f[e] = (short)hj1;
            float fb0 = bf2f(hb0), fj0 = bf2f(hj0);
            float fb1 = bf2f(hb1), fj1 = bf2f(hj1);
            nb0 = fmaf(fb0, fb0, nb0); bj0 = fmaf(fb0, fj0, bj0);
            nb1 = fmaf(fb1, fb1, nb1); bj1 = fmaf(fb1, fj1, bj1);
        }
        accP0 = __builtin_amdgcn_mfma_f32_16x16x32_bf16(au.h, b0f, accP0, 0, 0, 0);
        accQ0 = __builtin_amdgcn_mfma_f32_16x16x32_bf16(au.h, j0f, accQ0, 0, 0, 0);
        accP1 = __builtin_amdgcn_mfma_f32_16x16x32_bf16(au.h, b1f, accP1, 0, 0, 0);
        accQ1 = __builtin_amdgcn_mfma_f32_16x16x32_bf16(au.h, j1f, accQ1, 0, 0, 0);
    }
    // nb/bj: reduce across kb groups (masks 16,32 flip kb bits only; lr/t preserved)
#pragma unroll
    for (int mask = 16; mask < 64; mask <<= 1) {
        nb0 += __shfl_xor(nb0, mask); bj0 += __shfl_xor(bj0, mask);
        nb1 += __shfl_xor(nb1, mask); bj1 += __shfl_xor(bj1, mask);
    }

    const float qc = QCONST, qq = QCONST * QCONST;
    float nav[4];
#pragma unroll
    for (int r = 0; r < 4; r++) nav[r] = na2[w * 16 + kb * 4 + r];
    float es_r[4] = {0.f, 0.f, 0.f, 0.f}, rs_r[4] = {0.f, 0.f, 0.f, 0.f};

    {   // nt = 0
        int t = t0 + lr;
        float msk = (t < T_ROWS) ? 1.f : 0.f;
        float w1q4[4], w24[4];
#pragma unroll
        for (int r = 0; r < 4; r++) {
            float S = nav[r] + qq * nb0 - 2.f * qc * accP0[r];
            float xd = sqrtf(fmaxf(S, 0.f));
            float e = K0CONST * __expf(-xd);
            float dot = (accQ0[r] - qc * bj0) * msk;
            float w1 = e * dot, w2 = e * (1.f + xd);
            w1q4[r] = qc * w1; w24[r] = w2;
            es_r[r] += w2 * dot; rs_r[r] += w1;
        }
        float* wr = w12 + (size_t)t * 128 + w * 16 + kb * 4;
        *(float4*)wr = make_float4(w1q4[0], w1q4[1], w1q4[2], w1q4[3]);
        *(float4*)(wr + 64) = make_float4(w24[0], w24[1], w24[2], w24[3]);
    }
    {   // nt = 1
        int t = t0 + 16 + lr;
        float msk = (t < T_ROWS) ? 1.f : 0.f;
        float w1q4[4], w24[4];
#pragma unroll
        for (int r = 0; r < 4; r++) {
            float S = nav[r] + qq * nb1 - 2.f * qc * accP1[r];
            float xd = sqrtf(fmaxf(S, 0.f));
            float e = K0CONST * __expf(-xd);
            float dot = (accQ1[r] - qc * bj1) * msk;
            float w1 = e * dot, w2 = e * (1.f + xd);
            w1q4[r] = qc * w1; w24[r] = w2;
            es_r[r] += w2 * dot; rs_r[r] += w1;
        }
        float* wr = w12 + (size_t)t * 128 + w * 16 + kb * 4;
        *(float4*)wr = make_float4(w1q4[0], w1q4[1], w1q4[2], w1q4[3]);
        *(float4*)(wr + 64) = make_float4(w24[0], w24[1], w24[2], w24[3]);
    }
    // es/rs: reduce over t (lr bits)
#pragma unroll
    for (int mask = 1; mask < 16; mask <<= 1) {
#pragma unroll
        for (int r = 0; r < 4; r++) {
            es_r[r] += __shfl_xor(es_r[r], mask);
            rs_r[r] += __shfl_xor(rs_r[r], mask);
        }
    }
    if (lr == 0) {
#pragma unroll
        for (int r = 0; r < 4; r++) {
            es_p[blk * 64 + w * 16 + kb * 4 + r] = es_r[r];
            rs_p[blk * 64 + w * 16 + kb * 4 + r] = rs_r[r];
        }
    }
}

// ---------------- k_C: partial F[m][d] per t-chunk; lane=m, wave=d-slice ----------------
__global__ __launch_bounds__(896) void k_C(const float* __restrict__ Btr,
                                           const float* __restrict__ Jx,
                                           const float* __restrict__ w12,
                                           __half* __restrict__ pC) {  // [c][m][210]
    const int c = blockIdx.x;
    const int tid = threadIdx.x;
    const int lane = tid & 63;                                  // m
    const int wv = __builtin_amdgcn_readfirstlane(tid >> 6);    // 0..13
    const int d0 = wv * 15;
    const int tstart = c * TC_C;
    const int tend = min(tstart + TC_C, T_ROWS);

    float acc[15];
#pragma unroll
    for (int k = 0; k < 15; k++) acc[k] = 0.f;

#pragma unroll 2
    for (int t = tstart; t < tend; ++t) {
        float w1 = w12[(size_t)t * 128 + lane];
        float w2 = w12[(size_t)t * 128 + 64 + lane];
        const float* bp = Btr + (size_t)t * DESC + d0;  // uniform -> s_load
        const float* jp = Jx + (size_t)t * DESC + d0;
#pragma unroll
        for (int k = 0; k < 15; k++)
            acc[k] = fmaf(w1, bp[k], fmaf(w2, jp[k], acc[k]));
    }
    __half* op = pC + ((size_t)c * 64 + lane) * DESC + d0;
#pragma unroll
    for (int k = 0; k < 15; k++) op[k] = __float2half(acc[k]);
}

// ---------------- k_final: reduce partials, rank-1 term, force contraction ----------------
__global__ __launch_bounds__(256) void k_final(const float* __restrict__ Rs,
                                               const unsigned short* __restrict__ Abf,
                                               const float* __restrict__ es_p,
                                               const float* __restrict__ rs_p,
                                               const __half* __restrict__ pC,
                                               float* __restrict__ out) {
    const int m = blockIdx.x;
    const int tid = threadIdx.x;
    __shared__ float fsx[DESC];
    __shared__ float R[N_ATOMS * 3];
    __shared__ float s_rs, s_es;
    if (tid < N_ATOMS * 3) R[tid] = Rs[m * N_ATOMS * 3 + tid];
    if (tid >= 192) {  // wave 3: es/rs reduction
        int lx = tid - 192;
        float es = 0.f, rs = 0.f;
        for (int c2 = lx; c2 < NBLK_A; c2 += 64) {
            es += es_p[c2 * 64 + m];
            rs += rs_p[c2 * 64 + m];
        }
        for (int mask = 1; mask < 64; mask <<= 1) {
            es += __shfl_xor(es, mask);
            rs += __shfl_xor(rs, mask);
        }
        if (lx == 0) { s_es = es; s_rs = rs; }
    }
    float s = 0.f;
    if (tid < DESC) {
#pragma unroll 4
        for (int c2 = 0; c2 < NCH_C; c2++)
            s += __half2float(pC[((size_t)c2 * 64 + m) * DESC + tid]);
    }
    __syncthreads();
    if (tid < DESC) fsx[tid] = s_rs * bf2f(Abf[m * APAD + tid]) - s;  // STD = 1
    if (tid == 0) out[m] = s_es * (1.0f / QCONST);                    // Es = sum/q, C=0
    __syncthreads();
    if (tid < N_ATOMS * 3) {
        int b = tid / 3, kk = tid % 3;
        float acc = 0.f;
        for (int a = 0; a < N_ATOMS; a++) {
            if (a == b) continue;
            float dx = R[a * 3 + 0] - R[b * 3 + 0];
            float dy = R[a * 3 + 1] - R[b * 3 + 1];
            float dz = R[a * 3 + 2] - R[b * 3 + 2];
            float d2 = dx * dx + dy * dy + dz * dz;
            float dist = sqrtf(d2);
            float inv3 = 1.0f / (d2 * dist);
            int hi = (a > b) ? a : b, lo = (a > b) ? b : a;
            int p = hi * (hi - 1) / 2 + lo;
            float diffk = (kk == 0) ? dx : ((kk == 1) ? dy : dz);
            acc = fmaf(fsx[p] * inv3, diffk, acc);
        }
        out[BATCH + m * N_ATOMS * 3 + tid] = acc;
    }
}

extern "C" void kernel_launch(void* const* d_in, const int* in_sizes, int n_in,
                              void* d_out, int out_size, void* d_ws, size_t ws_size,
                              hipStream_t stream) {
    (void)in_sizes; (void)n_in; (void)out_size; (void)ws_size;
    const float* Rs = (const float*)d_in[0];
    const float* Btr = (const float*)d_in[1];
    const float* Jx = (const float*)d_in[2];
    float* out = (float*)d_out;

    char* ws = (char*)d_ws;
    unsigned short* Abf = (unsigned short*)ws;  ws += (size_t)BATCH * APAD * 2;   // 28.7 KB
    float* na2 = (float*)ws;                    ws += BATCH * 4;
    float* w12 = (float*)ws;                    ws += (size_t)TPAD * 128 * 4;     // 6.16 MB
    float* es_p = (float*)ws;                   ws += (size_t)NBLK_A * 64 * 4;    // 96 KB
    float* rs_p = (float*)ws;                   ws += (size_t)NBLK_A * 64 * 4;
    __half* pC = (__half*)ws;                   // 256*64*210*2 = 6.88 MB

    k_prep<<<dim3(BATCH), dim3(256), 0, stream>>>(Rs, Abf, na2);
    k_gemmA<<<dim3(NBLK_A), dim3(256), 0, stream>>>(Btr, Jx, Abf, na2, w12, es_p, rs_p);
    k_C<<<dim3(NCH_C), dim3(896), 0, stream>>>(Btr, Jx, w12, pC);
    k_final<<<dim3(BATCH), dim3(256), 0, stream>>>(Rs, Abf, es_p, rs_p, pC, out);
}

// Round 8
// 72.166 us; speedup vs baseline: 1.5103x; 1.5103x over previous
//
#include <hip/hip_runtime.h>
#include <hip/hip_fp16.h>
#include <math.h>

#define N_ATOMS 21
#define DESC 210
#define APAD 224            // padded descriptor length (7 x 32)
#define T_ROWS 12000
#define TPAD 12032
#define BATCH 64
#define NBLK_A 752          // gemmA blocks: 16 t each, 752*16 = 12032
#define NCH_C 256           // k_C t-chunks
#define TC_C 47             // 256*47 = 12032 >= 12000

#define QCONST 0.22360679774997896f   // sqrt(5)/10
#define K0CONST (1.0f/60.0f)          // 5/(3*sig^2)

typedef short bf16x8 __attribute__((ext_vector_type(8)));
typedef float f32x4 __attribute__((ext_vector_type(4)));

__device__ __forceinline__ float u2f(unsigned int u) {
    union { unsigned int u; float f; } x; x.u = u; return x.f;
}
__device__ __forceinline__ unsigned short f2bf(float f) {
    union { float f; unsigned int u; } x; x.f = f;
    unsigned int r = x.u + 0x7fffu + ((x.u >> 16) & 1u);  // RNE
    return (unsigned short)(r >> 16);
}
__device__ __forceinline__ float bf2f(unsigned short h) {
    return u2f((unsigned int)h << 16);
}

// ---------------- k_prep: Abf[m][224] = bf16(q/dist), na2 = ||bf16 row||^2 ----------------
__global__ __launch_bounds__(256) void k_prep(const float* __restrict__ Rs,
                                              unsigned short* __restrict__ Abf,
                                              float* __restrict__ na2) {
    int m = blockIdx.x;
    __shared__ float R[N_ATOMS * 3];
    __shared__ float red[256];
    int tid = threadIdx.x;
    if (tid < N_ATOMS * 3) R[tid] = Rs[m * N_ATOMS * 3 + tid];
    __syncthreads();
    float val = 0.f;
    if (tid < DESC) {
        int p = tid;
        int i = (int)((1.0f + sqrtf(1.0f + 8.0f * (float)p)) * 0.5f);
        while (i * (i - 1) / 2 > p) --i;
        while ((i + 1) * i / 2 <= p) ++i;
        int j = p - i * (i - 1) / 2;
        float dx = R[i * 3 + 0] - R[j * 3 + 0];
        float dy = R[i * 3 + 1] - R[j * 3 + 1];
        float dz = R[i * 3 + 2] - R[j * 3 + 2];
        float d = sqrtf(dx * dx + dy * dy + dz * dz);
        val = QCONST / d;
    }
    unsigned short h = f2bf(val);
    if (tid < APAD) Abf[m * APAD + tid] = h;
    float va = bf2f(h);
    red[tid] = va * va;
    __syncthreads();
    for (int s = 128; s > 0; s >>= 1) {
        if (tid < s) red[tid] += red[tid + s];
        __syncthreads();
    }
    if (tid == 0) na2[m] = red[0];
}

// ---------------- k_gemmA: LDS-staged bf16 MFMA; epilogue -> w1q/w2/es/rs ----------------
// 752 blocks x 256 thr (4 waves = 4 m-tiles of 16). Block = 16 t-rows.
// LDS rows padded to 232 bf16 (464 B, stride==20 mod 32 dwords -> <=2-way conflicts).
// Frag maps (R7-validated): A/B row=lane&15, k=(lane>>4)*8+e ; C/D col=lane&15(t), row=(lane>>4)*4+r (m).
#define BS_OFF 0        // 16 x 464 B
#define JS_OFF 7424
#define NB_OFF 14848    // 16 f32
#define BJ_OFF 14912    // 16 f32
#define NA_OFF 14976    // 64 f32
#define LDS_SZ 15232    // wtile [16][132] f32 aliases BS_OFF after barrier

__global__ __launch_bounds__(256) void k_gemmA(const float* __restrict__ Btr,
                                               const float* __restrict__ Jx,
                                               const unsigned short* __restrict__ Abf,
                                               const float* __restrict__ na2,
                                               float* __restrict__ w12,   // [TPAD][128]
                                               float* __restrict__ es_p,  // [NBLK_A][64]
                                               float* __restrict__ rs_p) {
    __shared__ char lds[LDS_SZ];
    const int blk = blockIdx.x;
    const int t0 = blk * 16;
    const int tid = threadIdx.x;
    const int lane = tid & 63;
    const int w = __builtin_amdgcn_readfirstlane(tid >> 6);  // m-tile 0..3
    const int lr = lane & 15;
    const int kb = lane >> 4;

    // A-frags hoisted to registers (28 VGPR), from L2-hot Abf
    uint4 au[7];
    {
        const unsigned short* ap = Abf + (w * 16 + lr) * APAD + kb * 8;
#pragma unroll
        for (int k8 = 0; k8 < 7; k8++) au[k8] = *(const uint4*)(ap + k8 * 32);
    }
    if (tid < 64) *(float*)(lds + NA_OFF + tid * 4) = na2[tid];

    // ---- stage: 16-lane group g stages row g of B and J (coalesced), + nb/bj ----
    {
        const int g = tid >> 4, gl = tid & 15;
        int tr = t0 + g; if (tr > T_ROWS - 1) tr = T_ROWS - 1;
        const float* bp = Btr + (size_t)tr * DESC;
        const float* jp = Jx + (size_t)tr * DESC;
        float nb = 0.f, bj = 0.f;
#pragma unroll
        for (int it = 0; it < 8; it++) {
            int c = it * 16 + gl;           // 4-B granule index within 232-elem row
            if (c < 116) {
                float2 vb = make_float2(0.f, 0.f), vj = make_float2(0.f, 0.f);
                if (c < 105) {
                    vb = *(const float2*)(bp + 2 * c);
                    vj = *(const float2*)(jp + 2 * c);
                }
                unsigned short hbx = f2bf(vb.x), hby = f2bf(vb.y);
                unsigned short hjx = f2bf(vj.x), hjy = f2bf(vj.y);
                *(unsigned int*)(lds + BS_OFF + g * 464 + c * 4) = (unsigned)hbx | ((unsigned)hby << 16);
                *(unsigned int*)(lds + JS_OFF + g * 464 + c * 4) = (unsigned)hjx | ((unsigned)hjy << 16);
                float fbx = bf2f(hbx), fby = bf2f(hby);
                float fjx = bf2f(hjx), fjy = bf2f(hjy);
                nb = fmaf(fbx, fbx, nb); nb = fmaf(fby, fby, nb);
                bj = fmaf(fbx, fjx, bj); bj = fmaf(fby, fjy, bj);
            }
        }
#pragma unroll
        for (int m = 1; m < 16; m <<= 1) { nb += __shfl_xor(nb, m); bj += __shfl_xor(bj, m); }
        if (gl == 0) {
            *(float*)(lds + NB_OFF + g * 4) = nb;
            *(float*)(lds + BJ_OFF + g * 4) = bj;
        }
    }
    __syncthreads();

    // ---- MFMA: P = A.B^T, Q = A.J^T over K = 224 ----
    f32x4 accP = {0.f, 0.f, 0.f, 0.f}, accQ = {0.f, 0.f, 0.f, 0.f};
#pragma unroll
    for (int k8 = 0; k8 < 7; k8++) {
        union { uint4 u; bf16x8 h; } bu, ju, a;
        bu.u = *(const uint4*)(lds + BS_OFF + lr * 464 + k8 * 64 + kb * 16);
        ju.u = *(const uint4*)(lds + JS_OFF + lr * 464 + k8 * 64 + kb * 16);
        a.u = au[k8];
        accP = __builtin_amdgcn_mfma_f32_16x16x32_bf16(a.h, bu.h, accP, 0, 0, 0);
        accQ = __builtin_amdgcn_mfma_f32_16x16x32_bf16(a.h, ju.h, accQ, 0, 0, 0);
    }

    // ---- epilogue ----
    const float nb_c = *(const float*)(lds + NB_OFF + lr * 4);
    const float bj_c = *(const float*)(lds + BJ_OFF + lr * 4);
    const float msk = (t0 + lr < T_ROWS) ? 1.f : 0.f;
    float w1q4[4], w24[4], es4[4], rs4[4];
#pragma unroll
    for (int r = 0; r < 4; r++) {
        float na = *(const float*)(lds + NA_OFF + (w * 16 + kb * 4 + r) * 4);
        float S = na + QCONST * QCONST * nb_c - 2.f * QCONST * accP[r];
        float xd = sqrtf(fmaxf(S, 0.f));
        float e = K0CONST * __expf(-xd);
        float dot = (accQ[r] - QCONST * bj_c) * msk;
        float w1 = e * dot;
        float w2 = e * (1.f + xd);
        w1q4[r] = QCONST * w1; w24[r] = w2;
        es4[r] = w2 * dot; rs4[r] = w1;
    }
#pragma unroll
    for (int m = 1; m < 16; m <<= 1) {
#pragma unroll
        for (int r = 0; r < 4; r++) {
            es4[r] += __shfl_xor(es4[r], m);
            rs4[r] += __shfl_xor(rs4[r], m);
        }
    }
    if (lr == 0) {
#pragma unroll
        for (int r = 0; r < 4; r++) {
            es_p[blk * 64 + w * 16 + kb * 4 + r] = es4[r];
            rs_p[blk * 64 + w * 16 + kb * 4 + r] = rs4[r];
        }
    }
    __syncthreads();  // all waves done reading Bs/Js -> safe to alias wtile
    {
        float* wt = (float*)lds;  // [16][132]
        *(float4*)(wt + lr * 132 + w * 16 + kb * 4) = make_float4(w1q4[0], w1q4[1], w1q4[2], w1q4[3]);
        *(float4*)(wt + lr * 132 + 64 + w * 16 + kb * 4) = make_float4(w24[0], w24[1], w24[2], w24[3]);
    }
    __syncthreads();
    {   // coalesced block store: contiguous 8 KB region of w12
        const float* wt = (const float*)lds;
        int row = tid >> 4, col = (tid & 15) * 8;
        float4 v0 = *(const float4*)(wt + row * 132 + col);
        float4 v1 = *(const float4*)(wt + row * 132 + col + 4);
        float* dst = w12 + (size_t)t0 * 128 + tid * 8;
        *(float4*)dst = v0;
        *(float4*)(dst + 4) = v1;
    }
}

// ---------------- k_C: lane = d (coalesced B/J), w via uniform s_load ----------------
// 512 blocks (256 chunks x 2 m-groups of 32) x 256 thr.
__global__ __launch_bounds__(256) void k_C(const float* __restrict__ Btr,
                                           const float* __restrict__ Jx,
                                           const float* __restrict__ w12,
                                           __half* __restrict__ pC) {  // [c][64 m][210 d]
    const int blk = blockIdx.x;
    const int c = blk >> 1;
    const int mg = blk & 1;
    const int d = threadIdx.x;
    const int dc = d < DESC ? d : (DESC - 1);
    const int tstart = c * TC_C;
    const int tend = min(tstart + TC_C, T_ROWS);

    float acc[32];
#pragma unroll
    for (int k = 0; k < 32; k++) acc[k] = 0.f;

    for (int t = tstart; t < tend; ++t) {
        float vb = Btr[(size_t)t * DESC + dc];
        float vj = Jx[(size_t)t * DESC + dc];
        const float* wp = w12 + (size_t)t * 128 + mg * 32;  // uniform -> s_load
#pragma unroll
        for (int k = 0; k < 32; k++)
            acc[k] = fmaf(wp[k], vb, fmaf(wp[64 + k], vj, acc[k]));
    }
    if (d < DESC) {
#pragma unroll
        for (int k = 0; k < 32; k++)
            pC[((size_t)c * 64 + mg * 32 + k) * DESC + d] = __float2half(acc[k]);
    }
}

// ---------------- k_final: reduce partials, rank-1 term, force contraction ----------------
__global__ __launch_bounds__(256) void k_final(const float* __restrict__ Rs,
                                               const unsigned short* __restrict__ Abf,
                                               const float* __restrict__ es_p,
                                               const float* __restrict__ rs_p,
                                               const __half* __restrict__ pC,
                                               float* __restrict__ out) {
    const int m = blockIdx.x;
    const int tid = threadIdx.x;
    __shared__ float fsx[DESC];
    __shared__ float R[N_ATOMS * 3];
    __shared__ float s_rs, s_es;
    if (tid < N_ATOMS * 3) R[tid] = Rs[m * N_ATOMS * 3 + tid];
    if (tid >= 192) {  // wave 3: es/rs reduction
        int lx = tid - 192;
        float es = 0.f, rs = 0.f;
        for (int c2 = lx; c2 < NBLK_A; c2 += 64) {
            es += es_p[c2 * 64 + m];
            rs += rs_p[c2 * 64 + m];
        }
        for (int mask = 1; mask < 64; mask <<= 1) {
            es += __shfl_xor(es, mask);
            rs += __shfl_xor(rs, mask);
        }
        if (lx == 0) { s_es = es; s_rs = rs; }
    }
    float s = 0.f;
    if (tid < DESC) {
#pragma unroll 4
        for (int c2 = 0; c2 < NCH_C; c2++)
            s += __half2float(pC[((size_t)c2 * 64 + m) * DESC + tid]);
    }
    __syncthreads();
    if (tid < DESC) fsx[tid] = s_rs * bf2f(Abf[m * APAD + tid]) - s;  // STD = 1
    if (tid == 0) out[m] = s_es * (1.0f / QCONST);                    // Es = sum/q, C=0
    __syncthreads();
    if (tid < N_ATOMS * 3) {
        int b = tid / 3, kk = tid % 3;
        float acc = 0.f;
        for (int a = 0; a < N_ATOMS; a++) {
            if (a == b) continue;
            float dx = R[a * 3 + 0] - R[b * 3 + 0];
            float dy = R[a * 3 + 1] - R[b * 3 + 1];
            float dz = R[a * 3 + 2] - R[b * 3 + 2];
            float d2 = dx * dx + dy * dy + dz * dz;
            float dist = sqrtf(d2);
            float inv3 = 1.0f / (d2 * dist);
            int hi = (a > b) ? a : b, lo = (a > b) ? b : a;
            int p = hi * (hi - 1) / 2 + lo;
            float diffk = (kk == 0) ? dx : ((kk == 1) ? dy : dz);
            acc = fmaf(fsx[p] * inv3, diffk, acc);
        }
        out[BATCH + m * N_ATOMS * 3 + tid] = acc;
    }
}

extern "C" void kernel_launch(void* const* d_in, const int* in_sizes, int n_in,
                              void* d_out, int out_size, void* d_ws, size_t ws_size,
                              hipStream_t stream) {
    (void)in_sizes; (void)n_in; (void)out_size; (void)ws_size;
    const float* Rs = (const float*)d_in[0];
    const float* Btr = (const float*)d_in[1];
    const float* Jx = (const float*)d_in[2];
    float* out = (float*)d_out;

    char* ws = (char*)d_ws;
    unsigned short* Abf = (unsigned short*)ws;  ws += (size_t)BATCH * APAD * 2;   // 28.7 KB
    float* na2 = (float*)ws;                    ws += BATCH * 4;
    float* w12 = (float*)ws;                    ws += (size_t)TPAD * 128 * 4;     // 6.16 MB
    float* es_p = (float*)ws;                   ws += (size_t)NBLK_A * 64 * 4;    // 192 KB
    float* rs_p = (float*)ws;                   ws += (size_t)NBLK_A * 64 * 4;    // 192 KB
    __half* pC = (__half*)ws;                   // 256*64*210*2 = 6.88 MB

    k_prep<<<dim3(BATCH), dim3(256), 0, stream>>>(Rs, Abf, na2);
    k_gemmA<<<dim3(NBLK_A), dim3(256), 0, stream>>>(Btr, Jx, Abf, na2, w12, es_p, rs_p);
    k_C<<<dim3(NCH_C * 2), dim3(256), 0, stream>>>(Btr, Jx, w12, pC);
    k_final<<<dim3(BATCH), dim3(256), 0, stream>>>(Rs, Abf, es_p, rs_p, pC, out);
}

// Round 9
// 53.969 us; speedup vs baseline: 2.0195x; 1.3372x over previous
//
#include <hip/hip_runtime.h>
#include <hip/hip_fp16.h>
#include <math.h>

#define N_ATOMS 21
#define DESC 210
#define APAD 224            // padded descriptor length (7 x 32)
#define T_ROWS 12000
#define TPAD 12032
#define BATCH 64
#define NBLK_A 376          // gemmA blocks: 32 t each, 376*32 = 12032
#define NCH_C 240           // k_C t-chunks (240*50 = 12000 exact)
#define TC_C 50
#define PCW 216             // pC padded row (27 x 8 halfs)

#define QCONST 0.22360679774997896f   // sqrt(5)/10
#define K0CONST (1.0f/60.0f)          // 5/(3*sig^2)

typedef short bf16x8 __attribute__((ext_vector_type(8)));
typedef float f32x4 __attribute__((ext_vector_type(4)));

__device__ __forceinline__ float u2f(unsigned int u) {
    union { unsigned int u; float f; } x; x.u = u; return x.f;
}
__device__ __forceinline__ unsigned short f2bf(float f) {
    union { float f; unsigned int u; } x; x.f = f;
    unsigned int r = x.u + 0x7fffu + ((x.u >> 16) & 1u);  // RNE
    return (unsigned short)(r >> 16);
}
__device__ __forceinline__ float bf2f(unsigned short h) {
    return u2f((unsigned int)h << 16);
}

// ---------------- k_prep: Abf[m][224] = bf16(q/dist), na2 = ||bf16 row||^2 ----------------
__global__ __launch_bounds__(256) void k_prep(const float* __restrict__ Rs,
                                              unsigned short* __restrict__ Abf,
                                              float* __restrict__ na2) {
    int m = blockIdx.x;
    __shared__ float R[N_ATOMS * 3];
    __shared__ float red[256];
    int tid = threadIdx.x;
    if (tid < N_ATOMS * 3) R[tid] = Rs[m * N_ATOMS * 3 + tid];
    __syncthreads();
    float val = 0.f;
    if (tid < DESC) {
        int p = tid;
        int i = (int)((1.0f + sqrtf(1.0f + 8.0f * (float)p)) * 0.5f);
        while (i * (i - 1) / 2 > p) --i;
        while ((i + 1) * i / 2 <= p) ++i;
        int j = p - i * (i - 1) / 2;
        float dx = R[i * 3 + 0] - R[j * 3 + 0];
        float dy = R[i * 3 + 1] - R[j * 3 + 1];
        float dz = R[i * 3 + 2] - R[j * 3 + 2];
        float d = sqrtf(dx * dx + dy * dy + dz * dz);
        val = QCONST / d;
    }
    unsigned short h = f2bf(val);
    if (tid < APAD) Abf[m * APAD + tid] = h;
    float va = bf2f(h);
    red[tid] = va * va;
    __syncthreads();
    for (int s = 128; s > 0; s >>= 1) {
        if (tid < s) red[tid] += red[tid + s];
        __syncthreads();
    }
    if (tid == 0) na2[m] = red[0];
}

// ---------------- k_gemmA: LDS-staged bf16 MFMA, 32 t/block ----------------
// 376 blocks x 256 thr (4 waves = 4 m-tiles of 16). Block = 32 t-rows, 2 t-tiles/wave.
// LDS rows 464 B (116 dwords, ==20 mod 32 -> 2-way max conflict on b128 reads).
// Frag maps (R7/R8-validated): A/B row=lane&15, k=(lane>>4)*8+e ;
// C/D col=lane&15 (t), row=(lane>>4)*4+r (m).
#define BS_OFF 0        // 32 x 464
#define JS_OFF 14848    // 32 x 464
#define NB_OFF 29696    // 32 f32
#define BJ_OFF 29824    // 32 f32
#define NA_OFF 29952    // 64 f32
#define LDS_SZ 30208    // wtile [32][132] f32 (16896 B) aliases BS/JS after barrier

__global__ __launch_bounds__(256) void k_gemmA(const float* __restrict__ Btr,
                                               const float* __restrict__ Jx,
                                               const unsigned short* __restrict__ Abf,
                                               const float* __restrict__ na2,
                                               float* __restrict__ w12,   // [TPAD][128]
                                               float* __restrict__ es_p,  // [64][NBLK_A]
                                               float* __restrict__ rs_p) {
    __shared__ char lds[LDS_SZ];
    const int blk = blockIdx.x;
    const int t0 = blk * 32;
    const int tid = threadIdx.x;
    const int lane = tid & 63;
    const int w = __builtin_amdgcn_readfirstlane(tid >> 6);  // m-tile 0..3
    const int lr = lane & 15;
    const int kb = lane >> 4;

    // A-frags hoisted to registers (28 VGPR), L2-hot
    uint4 au[7];
    {
        const unsigned short* ap = Abf + (w * 16 + lr) * APAD + kb * 8;
#pragma unroll
        for (int k8 = 0; k8 < 7; k8++) au[k8] = *(const uint4*)(ap + k8 * 32);
    }
    if (tid < 64) *(float*)(lds + NA_OFF + tid * 4) = na2[tid];

    // ---- stage: 8-lane group per row, 32 rows; fold nb/bj ----
    {
        const int g = tid >> 3, gl = tid & 7;
        int tr = t0 + g; if (tr > T_ROWS - 1) tr = T_ROWS - 1;
        const float* bp = Btr + (size_t)tr * DESC;
        const float* jp = Jx + (size_t)tr * DESC;
        float nb = 0.f, bj = 0.f;
#pragma unroll
        for (int it = 0; it < 15; it++) {
            int c = it * 8 + gl;            // 4-B granule within 464-B row
            if (c < 116) {
                float2 vb = make_float2(0.f, 0.f), vj = make_float2(0.f, 0.f);
                if (c < 105) {
                    vb = *(const float2*)(bp + 2 * c);
                    vj = *(const float2*)(jp + 2 * c);
                }
                unsigned short hbx = f2bf(vb.x), hby = f2bf(vb.y);
                unsigned short hjx = f2bf(vj.x), hjy = f2bf(vj.y);
                *(unsigned int*)(lds + BS_OFF + g * 464 + c * 4) = (unsigned)hbx | ((unsigned)hby << 16);
                *(unsigned int*)(lds + JS_OFF + g * 464 + c * 4) = (unsigned)hjx | ((unsigned)hjy << 16);
                float fbx = bf2f(hbx), fby = bf2f(hby);
                float fjx = bf2f(hjx), fjy = bf2f(hjy);
                nb = fmaf(fbx, fbx, nb); nb = fmaf(fby, fby, nb);
                bj = fmaf(fbx, fjx, bj); bj = fmaf(fby, fjy, bj);
            }
        }
#pragma unroll
        for (int m = 1; m < 8; m <<= 1) { nb += __shfl_xor(nb, m); bj += __shfl_xor(bj, m); }
        if (gl == 0) {
            *(float*)(lds + NB_OFF + g * 4) = nb;
            *(float*)(lds + BJ_OFF + g * 4) = bj;
        }
    }
    __syncthreads();

    // ---- MFMA: P = A.B^T, Q = A.J^T over K = 224, 2 t-tiles ----
    f32x4 accP[2] = {{0.f,0.f,0.f,0.f},{0.f,0.f,0.f,0.f}};
    f32x4 accQ[2] = {{0.f,0.f,0.f,0.f},{0.f,0.f,0.f,0.f}};
#pragma unroll
    for (int k8 = 0; k8 < 7; k8++) {
        union { uint4 u; bf16x8 h; } a;
        a.u = au[k8];
#pragma unroll
        for (int nt = 0; nt < 2; nt++) {
            union { uint4 u; bf16x8 h; } bu, ju;
            const int ro = (nt * 16 + lr) * 464 + k8 * 64 + kb * 16;
            bu.u = *(const uint4*)(lds + BS_OFF + ro);
            ju.u = *(const uint4*)(lds + JS_OFF + ro);
            accP[nt] = __builtin_amdgcn_mfma_f32_16x16x32_bf16(a.h, bu.h, accP[nt], 0, 0, 0);
            accQ[nt] = __builtin_amdgcn_mfma_f32_16x16x32_bf16(a.h, ju.h, accQ[nt], 0, 0, 0);
        }
    }

    // ---- epilogue ----
    float na4[4];
#pragma unroll
    for (int r = 0; r < 4; r++)
        na4[r] = *(const float*)(lds + NA_OFF + (w * 16 + kb * 4 + r) * 4);
    float es4[4] = {0.f,0.f,0.f,0.f}, rs4[4] = {0.f,0.f,0.f,0.f};
    float w1q4[2][4], w24[2][4];
#pragma unroll
    for (int nt = 0; nt < 2; nt++) {
        const int row = nt * 16 + lr;
        const float nb_c = *(const float*)(lds + NB_OFF + row * 4);
        const float bj_c = *(const float*)(lds + BJ_OFF + row * 4);
        const float msk = (t0 + row < T_ROWS) ? 1.f : 0.f;
#pragma unroll
        for (int r = 0; r < 4; r++) {
            float S = na4[r] + QCONST * QCONST * nb_c - 2.f * QCONST * accP[nt][r];
            float xd = sqrtf(fmaxf(S, 0.f));
            float e = K0CONST * __expf(-xd);
            float dot = (accQ[nt][r] - QCONST * bj_c) * msk;
            float w1 = e * dot;
            float w2 = e * (1.f + xd);
            w1q4[nt][r] = QCONST * w1; w24[nt][r] = w2;
            es4[r] += w2 * dot; rs4[r] += w1;
        }
    }
#pragma unroll
    for (int m = 1; m < 16; m <<= 1) {
#pragma unroll
        for (int r = 0; r < 4; r++) {
            es4[r] += __shfl_xor(es4[r], m);
            rs4[r] += __shfl_xor(rs4[r], m);
        }
    }
    if (lr == 0) {
#pragma unroll
        for (int r = 0; r < 4; r++) {   // transposed: [m][blk]
            es_p[(size_t)(w * 16 + kb * 4 + r) * NBLK_A + blk] = es4[r];
            rs_p[(size_t)(w * 16 + kb * 4 + r) * NBLK_A + blk] = rs4[r];
        }
    }
    __syncthreads();  // everyone done reading Bs/Js -> alias wtile
    {
        float* wt = (float*)lds;  // [32][132]
#pragma unroll
        for (int nt = 0; nt < 2; nt++) {
            float* p = wt + (nt * 16 + lr) * 132 + w * 16 + kb * 4;
            *(float4*)p = make_float4(w1q4[nt][0], w1q4[nt][1], w1q4[nt][2], w1q4[nt][3]);
            *(float4*)(p + 64) = make_float4(w24[nt][0], w24[nt][1], w24[nt][2], w24[nt][3]);
        }
    }
    __syncthreads();
    {   // coalesced 16-KB contiguous store of w12[t0..t0+32)
        const float* wt = (const float*)lds;
        const int row = tid >> 3, coloff = (tid & 7) * 16;
        float* dst = w12 + (size_t)(t0 + row) * 128 + coloff;
#pragma unroll
        for (int v = 0; v < 4; v++)
            *(float4*)(dst + v * 4) = *(const float4*)(wt + row * 132 + coloff + v * 4);
    }
}

// ---------------- k_C: lane = d (coalesced B/J), w via uniform s_load ----------------
// 480 blocks (240 chunks x 2 m-groups of 32) x 256 thr.
__global__ __launch_bounds__(256) void k_C(const float* __restrict__ Btr,
                                           const float* __restrict__ Jx,
                                           const float* __restrict__ w12,
                                           __half* __restrict__ pC) {  // [c][64 m][216]
    const int blk = blockIdx.x;
    const int c = blk >> 1;
    const int mg = blk & 1;
    const int d = threadIdx.x;
    const int dc = d < DESC ? d : (DESC - 1);
    const int tstart = c * TC_C;
    const int tend = tstart + TC_C;

    float acc[32];
#pragma unroll
    for (int k = 0; k < 32; k++) acc[k] = 0.f;

    for (int t = tstart; t < tend; ++t) {
        float vb = Btr[(size_t)t * DESC + dc];
        float vj = Jx[(size_t)t * DESC + dc];
        const float* wp = w12 + (size_t)t * 128 + mg * 32;  // uniform -> s_load
#pragma unroll
        for (int k = 0; k < 32; k++)
            acc[k] = fmaf(wp[k], vb, fmaf(wp[64 + k], vj, acc[k]));
    }
    if (d < PCW) {
        const float z = (d < DESC) ? 1.f : 0.f;
#pragma unroll
        for (int k = 0; k < 32; k++)
            pC[((size_t)c * 64 + mg * 32 + k) * PCW + d] = __float2half(acc[k] * z);
    }
}

// ---------------- k_final: ILP'd c-reduction, rank-1 term, force contraction ----------------
__global__ __launch_bounds__(256) void k_final(const float* __restrict__ Rs,
                                               const unsigned short* __restrict__ Abf,
                                               const float* __restrict__ es_p,
                                               const float* __restrict__ rs_p,
                                               const __half* __restrict__ pC,
                                               float* __restrict__ out) {
    const int m = blockIdx.x;
    const int tid = threadIdx.x;
    __shared__ float parts[27][7][8];   // [octet][c-group][elem]
    __shared__ float fsx[DESC];
    __shared__ float R[N_ATOMS * 3];
    __shared__ float s_rs, s_es;
    if (tid < N_ATOMS * 3) R[tid] = Rs[m * N_ATOMS * 3 + tid];
    if (tid >= 192) {  // wave 3: es/rs (contiguous reads after transpose)
        int lx = tid - 192;
        float es = 0.f, rs = 0.f;
        for (int c2 = lx; c2 < NBLK_A; c2 += 64) {
            es += es_p[(size_t)m * NBLK_A + c2];
            rs += rs_p[(size_t)m * NBLK_A + c2];
        }
        for (int mask = 1; mask < 64; mask <<= 1) {
            es += __shfl_xor(es, mask);
            rs += __shfl_xor(rs, mask);
        }
        if (lx == 0) { s_es = es; s_rs = rs; }
    } else if (tid < 189) {  // 27 octets x 7 c-groups, uint4 loads (16-way ILP)
        const int o = tid % 27, cg = tid / 27;
        float facc[8];
#pragma unroll
        for (int e = 0; e < 8; e++) facc[e] = 0.f;
#pragma unroll 4
        for (int c = cg; c < NCH_C; c += 7) {
            uint4 v = *(const uint4*)(pC + ((size_t)c * 64 + m) * PCW + o * 8);
            const __half2* h = (const __half2*)&v;
#pragma unroll
            for (int p2 = 0; p2 < 4; p2++) {
                float2 f = __half22float2(h[p2]);
                facc[p2 * 2] += f.x;
                facc[p2 * 2 + 1] += f.y;
            }
        }
#pragma unroll
        for (int e = 0; e < 8; e++) parts[o][cg][e] = facc[e];
    }
    __syncthreads();
    if (tid < DESC) {
        float s = 0.f;
        const int o = tid >> 3, e = tid & 7;
#pragma unroll
        for (int cg = 0; cg < 7; cg++) s += parts[o][cg][e];
        fsx[tid] = s_rs * bf2f(Abf[m * APAD + tid]) - s;  // STD = 1
    }
    if (tid == 0) out[m] = s_es * (1.0f / QCONST);        // Es = sum/q, C=0
    __syncthreads();
    if (tid < N_ATOMS * 3) {
        int b = tid / 3, kk = tid % 3;
        float acc = 0.f;
        for (int a = 0; a < N_ATOMS; a++) {
            if (a == b) continue;
            float dx = R[a * 3 + 0] - R[b * 3 + 0];
            float dy = R[a * 3 + 1] - R[b * 3 + 1];
            float dz = R[a * 3 + 2] - R[b * 3 + 2];
            float d2 = dx * dx + dy * dy + dz * dz;
            float dist = sqrtf(d2);
            float inv3 = 1.0f / (d2 * dist);
            int hi = (a > b) ? a : b, lo = (a > b) ? b : a;
            int p = hi * (hi - 1) / 2 + lo;
            float diffk = (kk == 0) ? dx : ((kk == 1) ? dy : dz);
            acc = fmaf(fsx[p] * inv3, diffk, acc);
        }
        out[BATCH + m * N_ATOMS * 3 + tid] = acc;
    }
}

extern "C" void kernel_launch(void* const* d_in, const int* in_sizes, int n_in,
                              void* d_out, int out_size, void* d_ws, size_t ws_size,
                              hipStream_t stream) {
    (void)in_sizes; (void)n_in; (void)out_size; (void)ws_size;
    const float* Rs = (const float*)d_in[0];
    const float* Btr = (const float*)d_in[1];
    const float* Jx = (const float*)d_in[2];
    float* out = (float*)d_out;

    char* ws = (char*)d_ws;
    unsigned short* Abf = (unsigned short*)ws;  ws += (size_t)BATCH * APAD * 2;   // 28.7 KB
    float* na2 = (float*)ws;                    ws += BATCH * 4;
    float* w12 = (float*)ws;                    ws += (size_t)TPAD * 128 * 4;     // 6.16 MB
    float* es_p = (float*)ws;                   ws += (size_t)BATCH * NBLK_A * 4; // 192 KB
    float* rs_p = (float*)ws;                   ws += (size_t)BATCH * NBLK_A * 4; // 192 KB
    __half* pC = (__half*)ws;                   // 240*64*216*2 = 6.64 MB

    k_prep<<<dim3(BATCH), dim3(256), 0, stream>>>(Rs, Abf, na2);
    k_gemmA<<<dim3(NBLK_A), dim3(256), 0, stream>>>(Btr, Jx, Abf, na2, w12, es_p, rs_p);
    k_C<<<dim3(NCH_C * 2), dim3(256), 0, stream>>>(Btr, Jx, w12, pC);
    k_final<<<dim3(BATCH), dim3(256), 0, stream>>>(Rs, Abf, es_p, rs_p, pC, out);
}

// Round 11
// 52.026 us; speedup vs baseline: 2.0950x; 1.0373x over previous
//
#include <hip/hip_runtime.h>
#include <hip/hip_fp16.h>
#include <math.h>

#define N_ATOMS 21
#define DESC 210
#define APAD 224            // padded descriptor length (7 x 32)
#define T_ROWS 12000
#define TPAD 12032
#define BATCH 64
#define NBLK_A 376          // fused blocks: 32 t each, 376*32 = 12032
#define PCW 216             // pC padded row (27 x 8 halfs)

#define QCONST 0.22360679774997896f   // sqrt(5)/10
#define K0CONST (1.0f/60.0f)          // 5/(3*sig^2)

typedef short bf16x8 __attribute__((ext_vector_type(8)));
typedef float f32x4 __attribute__((ext_vector_type(4)));

__device__ __forceinline__ float u2f(unsigned int u) {
    union { unsigned int u; float f; } x; x.u = u; return x.f;
}
__device__ __forceinline__ unsigned short f2bf(float f) {
    union { float f; unsigned int u; } x; x.f = f;
    unsigned int r = x.u + 0x7fffu + ((x.u >> 16) & 1u);  // RNE
    return (unsigned short)(r >> 16);
}
__device__ __forceinline__ float bf2f(unsigned short h) {
    return u2f((unsigned int)h << 16);
}

// ---------------- k_prep: Abf[m][224] = bf16(q/dist), na2 = ||bf16 row||^2 ----------------
__global__ __launch_bounds__(256) void k_prep(const float* __restrict__ Rs,
                                              unsigned short* __restrict__ Abf,
                                              float* __restrict__ na2) {
    int m = blockIdx.x;
    __shared__ float R[N_ATOMS * 3];
    __shared__ float red[256];
    int tid = threadIdx.x;
    if (tid < N_ATOMS * 3) R[tid] = Rs[m * N_ATOMS * 3 + tid];
    __syncthreads();
    float val = 0.f;
    if (tid < DESC) {
        int p = tid;
        int i = (int)((1.0f + sqrtf(1.0f + 8.0f * (float)p)) * 0.5f);
        while (i * (i - 1) / 2 > p) --i;
        while ((i + 1) * i / 2 <= p) ++i;
        int j = p - i * (i - 1) / 2;
        float dx = R[i * 3 + 0] - R[j * 3 + 0];
        float dy = R[i * 3 + 1] - R[j * 3 + 1];
        float dz = R[i * 3 + 2] - R[j * 3 + 2];
        float d = sqrtf(dx * dx + dy * dy + dz * dz);
        val = QCONST / d;
    }
    unsigned short h = f2bf(val);
    if (tid < APAD) Abf[m * APAD + tid] = h;
    float va = bf2f(h);
    red[tid] = va * va;
    __syncthreads();
    for (int s = 128; s > 0; s >>= 1) {
        if (tid < s) red[tid] += red[tid + s];
        __syncthreads();
    }
    if (tid == 0) na2[m] = red[0];
}

// ---------------- k_fused: MFMA phase A + epilogue + phase C, one block = 32 t ----------------
// 376 blocks x 256 thr (4 waves). Phase A: wave = m-tile of 16 (MFMA 16x16x32).
// Phase C: lane = m (64), wave = 54-wide d-slice; w from LDS, B/J via uniform s_loads.
// Frag maps (R7/R8-validated): A/B row=lane&15, k=(lane>>4)*8+e ;
// C/D col=lane&15 (t), row=(lane>>4)*4+r (m).
#define BS_OFF 0        // 32 x 464 B
#define JS_OFF 14848    // 32 x 464 B
#define NB_OFF 29696    // 32 f32
#define BJ_OFF 29824    // 32 f32
#define NA_OFF 29952    // 64 f32
#define LDS_SZ 30208    // wtile [32][132] f32 (16896 B) aliases BS/JS after barrier

__global__ __launch_bounds__(256) void k_fused(const float* __restrict__ Btr,
                                               const float* __restrict__ Jx,
                                               const unsigned short* __restrict__ Abf,
                                               const float* __restrict__ na2,
                                               float* __restrict__ es_p,  // [64][NBLK_A]
                                               float* __restrict__ rs_p,
                                               __half* __restrict__ pC) { // [blk][64][216]
    __shared__ char lds[LDS_SZ];
    const int blk = blockIdx.x;
    const int t0 = blk * 32;
    const int tid = threadIdx.x;
    const int lane = tid & 63;
    const int w = __builtin_amdgcn_readfirstlane(tid >> 6);  // wave id 0..3
    const int lr = lane & 15;
    const int kb = lane >> 4;

    // A-frags hoisted to registers, L2-hot
    uint4 au[7];
    {
        const unsigned short* ap = Abf + (w * 16 + lr) * APAD + kb * 8;
#pragma unroll
        for (int k8 = 0; k8 < 7; k8++) au[k8] = *(const uint4*)(ap + k8 * 32);
    }
    if (tid < 64) *(float*)(lds + NA_OFF + tid * 4) = na2[tid];

    // ---- stage: 8-lane group per row, 32 rows; fold nb/bj ----
    {
        const int g = tid >> 3, gl = tid & 7;
        int tr = t0 + g; if (tr > T_ROWS - 1) tr = T_ROWS - 1;
        const float* bp = Btr + (size_t)tr * DESC;
        const float* jp = Jx + (size_t)tr * DESC;
        float nb = 0.f, bj = 0.f;
#pragma unroll
        for (int it = 0; it < 15; it++) {
            int c = it * 8 + gl;            // 4-B granule within 464-B row
            if (c < 116) {
                float2 vb = make_float2(0.f, 0.f), vj = make_float2(0.f, 0.f);
                if (c < 105) {
                    vb = *(const float2*)(bp + 2 * c);
                    vj = *(const float2*)(jp + 2 * c);
                }
                unsigned short hbx = f2bf(vb.x), hby = f2bf(vb.y);
                unsigned short hjx = f2bf(vj.x), hjy = f2bf(vj.y);
                *(unsigned int*)(lds + BS_OFF + g * 464 + c * 4) = (unsigned)hbx | ((unsigned)hby << 16);
                *(unsigned int*)(lds + JS_OFF + g * 464 + c * 4) = (unsigned)hjx | ((unsigned)hjy << 16);
                float fbx = bf2f(hbx), fby = bf2f(hby);
                float fjx = bf2f(hjx), fjy = bf2f(hjy);
                nb = fmaf(fbx, fbx, nb); nb = fmaf(fby, fby, nb);
                bj = fmaf(fbx, fjx, bj); bj = fmaf(fby, fjy, bj);
            }
        }
#pragma unroll
        for (int m = 1; m < 8; m <<= 1) { nb += __shfl_xor(nb, m); bj += __shfl_xor(bj, m); }
        if (gl == 0) {
            *(float*)(lds + NB_OFF + g * 4) = nb;
            *(float*)(lds + BJ_OFF + g * 4) = bj;
        }
    }
    __syncthreads();

    // ---- MFMA: P = A.B^T, Q = A.J^T over K = 224, 2 t-tiles ----
    f32x4 accP[2] = {{0.f,0.f,0.f,0.f},{0.f,0.f,0.f,0.f}};
    f32x4 accQ[2] = {{0.f,0.f,0.f,0.f},{0.f,0.f,0.f,0.f}};
#pragma unroll
    for (int k8 = 0; k8 < 7; k8++) {
        union { uint4 u; bf16x8 h; } a;
        a.u = au[k8];
#pragma unroll
        for (int nt = 0; nt < 2; nt++) {
            union { uint4 u; bf16x8 h; } bu, ju;
            const int ro = (nt * 16 + lr) * 464 + k8 * 64 + kb * 16;
            bu.u = *(const uint4*)(lds + BS_OFF + ro);
            ju.u = *(const uint4*)(lds + JS_OFF + ro);
            accP[nt] = __builtin_amdgcn_mfma_f32_16x16x32_bf16(a.h, bu.h, accP[nt], 0, 0, 0);
            accQ[nt] = __builtin_amdgcn_mfma_f32_16x16x32_bf16(a.h, ju.h, accQ[nt], 0, 0, 0);
        }
    }

    // ---- epilogue: w1q/w2/es/rs ----
    float na4[4];
#pragma unroll
    for (int r = 0; r < 4; r++)
        na4[r] = *(const float*)(lds + NA_OFF + (w * 16 + kb * 4 + r) * 4);
    float es4[4] = {0.f,0.f,0.f,0.f}, rs4[4] = {0.f,0.f,0.f,0.f};
    float w1q4[2][4], w24[2][4];
#pragma unroll
    for (int nt = 0; nt < 2; nt++) {
        const int row = nt * 16 + lr;
        const float nb_c = *(const float*)(lds + NB_OFF + row * 4);
        const float bj_c = *(const float*)(lds + BJ_OFF + row * 4);
        const float msk = (t0 + row < T_ROWS) ? 1.f : 0.f;
#pragma unroll
        for (int r = 0; r < 4; r++) {
            float S = na4[r] + QCONST * QCONST * nb_c - 2.f * QCONST * accP[nt][r];
            float xd = sqrtf(fmaxf(S, 0.f));
            float e = K0CONST * __expf(-xd);
            float dot = (accQ[nt][r] - QCONST * bj_c) * msk;
            float w1 = e * dot;
            float w2 = e * (1.f + xd) * msk;  // MASKED: pad rows must not feed phase C's F2
            w1q4[nt][r] = QCONST * w1; w24[nt][r] = w2;
            es4[r] += w2 * dot; rs4[r] += w1;
        }
    }
#pragma unroll
    for (int m = 1; m < 16; m <<= 1) {
#pragma unroll
        for (int r = 0; r < 4; r++) {
            es4[r] += __shfl_xor(es4[r], m);
            rs4[r] += __shfl_xor(rs4[r], m);
        }
    }
    if (lr == 0) {
#pragma unroll
        for (int r = 0; r < 4; r++) {   // transposed: [m][blk]
            es_p[(size_t)(w * 16 + kb * 4 + r) * NBLK_A + blk] = es4[r];
            rs_p[(size_t)(w * 16 + kb * 4 + r) * NBLK_A + blk] = rs4[r];
        }
    }
    __syncthreads();  // everyone done reading Bs/Js -> alias wtile
    {
        float* wt = (float*)lds;  // [32][132]
#pragma unroll
        for (int nt = 0; nt < 2; nt++) {
            float* p = wt + (nt * 16 + lr) * 132 + w * 16 + kb * 4;
            *(float4*)p = make_float4(w1q4[nt][0], w1q4[nt][1], w1q4[nt][2], w1q4[nt][3]);
            *(float4*)(p + 64) = make_float4(w24[nt][0], w24[nt][1], w24[nt][2], w24[nt][3]);
        }
    }
    __syncthreads();

    // ---- phase C: acc[m=lane][d0..d0+54) = sum_t w1q*b + w2*j  (B/J via s_load, L2-hot) ----
    {
        const float* wt = (const float*)lds;
        const int d0 = w * 54;          // waves cover 216 = PCW
        float acc[54];
#pragma unroll
        for (int k = 0; k < 54; k++) acc[k] = 0.f;

        if (d0 + 54 <= DESC) {          // waves 0..2: contiguous uniform loads
            for (int t = 0; t < 32; ++t) {
                int tg = t0 + t; if (tg > T_ROWS - 1) tg = T_ROWS - 1;
                const float w1 = wt[t * 132 + lane];
                const float w2 = wt[t * 132 + 64 + lane];
                const float* bp = Btr + (size_t)tg * DESC + d0;  // uniform -> s_load
                const float* jp = Jx + (size_t)tg * DESC + d0;
#pragma unroll
                for (int k = 0; k < 54; k++)
                    acc[k] = fmaf(w1, bp[k], fmaf(w2, jp[k], acc[k]));
            }
        } else {                        // wave 3: clamp d >= DESC (pad zeroed at write)
            for (int t = 0; t < 32; ++t) {
                int tg = t0 + t; if (tg > T_ROWS - 1) tg = T_ROWS - 1;
                const float w1 = wt[t * 132 + lane];
                const float w2 = wt[t * 132 + 64 + lane];
                const float* bp = Btr + (size_t)tg * DESC;
                const float* jp = Jx + (size_t)tg * DESC;
#pragma unroll
                for (int k = 0; k < 48; k++)
                    acc[k] = fmaf(w1, bp[d0 + k], fmaf(w2, jp[d0 + k], acc[k]));
            }
        }
        __half* op = pC + ((size_t)blk * 64 + lane) * PCW + d0;
#pragma unroll
        for (int k = 0; k < 54; k += 2) {
            float a0 = (d0 + k < DESC) ? acc[k] : 0.f;
            float a1 = (d0 + k + 1 < DESC) ? acc[k + 1] : 0.f;
            *(__half2*)(op + k) = __floats2half2_rn(a0, a1);
        }
    }
}

// ---------------- k_final: ILP'd c-reduction, rank-1 term, force contraction ----------------
__global__ __launch_bounds__(256) void k_final(const float* __restrict__ Rs,
                                               const unsigned short* __restrict__ Abf,
                                               const float* __restrict__ es_p,
                                               const float* __restrict__ rs_p,
                                               const __half* __restrict__ pC,
                                               float* __restrict__ out) {
    const int m = blockIdx.x;
    const int tid = threadIdx.x;
    __shared__ float parts[27][7][8];   // [octet][c-group][elem]
    __shared__ float fsx[DESC];
    __shared__ float R[N_ATOMS * 3];
    __shared__ float s_rs, s_es;
    if (tid < N_ATOMS * 3) R[tid] = Rs[m * N_ATOMS * 3 + tid];
    if (tid >= 192) {  // wave 3: es/rs (contiguous reads)
        int lx = tid - 192;
        float es = 0.f, rs = 0.f;
        for (int c2 = lx; c2 < NBLK_A; c2 += 64) {
            es += es_p[(size_t)m * NBLK_A + c2];
            rs += rs_p[(size_t)m * NBLK_A + c2];
        }
        for (int mask = 1; mask < 64; mask <<= 1) {
            es += __shfl_xor(es, mask);
            rs += __shfl_xor(rs, mask);
        }
        if (lx == 0) { s_es = es; s_rs = rs; }
    } else if (tid < 189) {  // 27 octets x 7 c-groups, uint4 loads (16-way ILP)
        const int o = tid % 27, cg = tid / 27;
        float facc[8];
#pragma unroll
        for (int e = 0; e < 8; e++) facc[e] = 0.f;
#pragma unroll 4
        for (int c = cg; c < NBLK_A; c += 7) {
            uint4 v = *(const uint4*)(pC + ((size_t)c * 64 + m) * PCW + o * 8);
            const __half2* h = (const __half2*)&v;
#pragma unroll
            for (int p2 = 0; p2 < 4; p2++) {
                float2 f = __half22float2(h[p2]);
                facc[p2 * 2] += f.x;
                facc[p2 * 2 + 1] += f.y;
            }
        }
#pragma unroll
        for (int e = 0; e < 8; e++) parts[o][cg][e] = facc[e];
    }
    __syncthreads();
    if (tid < DESC) {
        float s = 0.f;
        const int o = tid >> 3, e = tid & 7;
#pragma unroll
        for (int cg = 0; cg < 7; cg++) s += parts[o][cg][e];
        fsx[tid] = s_rs * bf2f(Abf[m * APAD + tid]) - s;  // STD = 1
    }
    if (tid == 0) out[m] = s_es * (1.0f / QCONST);        // Es = sum/q, C=0
    __syncthreads();
    if (tid < N_ATOMS * 3) {
        int b = tid / 3, kk = tid % 3;
        float acc = 0.f;
        for (int a = 0; a < N_ATOMS; a++) {
            if (a == b) continue;
            float dx = R[a * 3 + 0] - R[b * 3 + 0];
            float dy = R[a * 3 + 1] - R[b * 3 + 1];
            float dz = R[a * 3 + 2] - R[b * 3 + 2];
            float d2 = dx * dx + dy * dy + dz * dz;
            float dist = sqrtf(d2);
            float inv3 = 1.0f / (d2 * dist);
            int hi = (a > b) ? a : b, lo = (a > b) ? b : a;
            int p = hi * (hi - 1) / 2 + lo;
            float diffk = (kk == 0) ? dx : ((kk == 1) ? dy : dz);
            acc = fmaf(fsx[p] * inv3, diffk, acc);
        }
        out[BATCH + m * N_ATOMS * 3 + tid] = acc;
    }
}

extern "C" void kernel_launch(void* const* d_in, const int* in_sizes, int n_in,
                              void* d_out, int out_size, void* d_ws, size_t ws_size,
                              hipStream_t stream) {
    (void)in_sizes; (void)n_in; (void)out_size; (void)ws_size;
    const float* Rs = (const float*)d_in[0];
    const float* Btr = (const float*)d_in[1];
    const float* Jx = (const float*)d_in[2];
    float* out = (float*)d_out;

    char* ws = (char*)d_ws;
    unsigned short* Abf = (unsigned short*)ws;  ws += (size_t)BATCH * APAD * 2;   // 28.7 KB
    float* na2 = (float*)ws;                    ws += BATCH * 4;
    float* es_p = (float*)ws;                   ws += (size_t)BATCH * NBLK_A * 4; // 96 KB
    float* rs_p = (float*)ws;                   ws += (size_t)BATCH * NBLK_A * 4; // 96 KB
    __half* pC = (__half*)ws;                   // 376*64*216*2 = 10.4 MB

    k_prep<<<dim3(BATCH), dim3(256), 0, stream>>>(Rs, Abf, na2);
    k_fused<<<dim3(NBLK_A), dim3(256), 0, stream>>>(Btr, Jx, Abf, na2, es_p, rs_p, pC);
    k_final<<<dim3(BATCH), dim3(256), 0, stream>>>(Rs, Abf, es_p, rs_p, pC, out);
}

// Round 12
// 36.819 us; speedup vs baseline: 2.9602x; 1.4130x over previous
//
#include <hip/hip_runtime.h>
#include <hip/hip_fp16.h>
#include <math.h>

#define N_ATOMS 21
#define DESC 210
#define APAD 224            // padded descriptor length (7 x 32)
#define T_ROWS 12000
#define BATCH 64
#define NBLK_A 376          // fused blocks: 32 t each, 376*32 = 12032
#define PCW 216             // pC padded row (27 x 8 halfs)

#define QCONST 0.22360679774997896f   // sqrt(5)/10
#define K0CONST (1.0f/60.0f)          // 5/(3*sig^2)

typedef short bf16x8 __attribute__((ext_vector_type(8)));
typedef float f32x4 __attribute__((ext_vector_type(4)));

__device__ __forceinline__ float u2f(unsigned int u) {
    union { unsigned int u; float f; } x; x.u = u; return x.f;
}
__device__ __forceinline__ unsigned short f2bf(float f) {
    union { float f; unsigned int u; } x; x.f = f;
    unsigned int r = x.u + 0x7fffu + ((x.u >> 16) & 1u);  // RNE
    return (unsigned short)(r >> 16);
}
__device__ __forceinline__ float bf2f(unsigned short h) {
    return u2f((unsigned int)h << 16);
}

// ---------------- k_prep: Abf[m][224] = bf16(q/dist), na2 = ||bf16 row||^2 ----------------
__global__ __launch_bounds__(256) void k_prep(const float* __restrict__ Rs,
                                              unsigned short* __restrict__ Abf,
                                              float* __restrict__ na2) {
    int m = blockIdx.x;
    __shared__ float R[N_ATOMS * 3];
    __shared__ float red[256];
    int tid = threadIdx.x;
    if (tid < N_ATOMS * 3) R[tid] = Rs[m * N_ATOMS * 3 + tid];
    __syncthreads();
    float val = 0.f;
    if (tid < DESC) {
        int p = tid;
        int i = (int)((1.0f + sqrtf(1.0f + 8.0f * (float)p)) * 0.5f);
        while (i * (i - 1) / 2 > p) --i;
        while ((i + 1) * i / 2 <= p) ++i;
        int j = p - i * (i - 1) / 2;
        float dx = R[i * 3 + 0] - R[j * 3 + 0];
        float dy = R[i * 3 + 1] - R[j * 3 + 1];
        float dz = R[i * 3 + 2] - R[j * 3 + 2];
        float d = sqrtf(dx * dx + dy * dy + dz * dz);
        val = QCONST / d;
    }
    unsigned short h = f2bf(val);
    if (tid < APAD) Abf[m * APAD + tid] = h;
    float va = bf2f(h);
    red[tid] = va * va;
    __syncthreads();
    for (int s = 128; s > 0; s >>= 1) {
        if (tid < s) red[tid] += red[tid + s];
        __syncthreads();
    }
    if (tid == 0) na2[m] = red[0];
}

// ---------------- k_fused: MFMA phase A + epilogue + MFMA phase C ----------------
// 376 blocks x 256 thr (4 waves). Block = 32 t-rows.
// Phase A: P=A.B^T, Q=A.J^T (wave = m-tile of 16).
// Phase C: D[64m][224d] = W[64m][64k] . X[64k][224d], K = {32 w1q|B rows, 32 w2|J rows},
//          via X^T LDS tile; wave = m-tile, 14 d-tiles x 2 MFMA.
// Frag maps (R7/R8-validated): A/B row|col=lane&15, k=(lane>>4)*8+e ;
// C/D col=lane&15, row=(lane>>4)*4+r.
#define BS_OFF 0        // 32 x 464 B   (B rows, bf16, 232-wide)
#define JS_OFF 14848    // 32 x 464 B
#define XT_OFF 29696    // 224 x 144 B  (X^T: row d, 64 k-cols bf16, padded to 72)
#define W_OFF  61952    // 64 x 144 B   (W: row m, 64 k-cols bf16)
#define NB_OFF 71168    // 32 f32
#define BJ_OFF 71296    // 32 f32
#define NA_OFF 71424    // 64 f32
#define LDS_SZ 71680    // D_lds [64][224] half (28672 B) aliases BS/JS after phase A

__global__ __launch_bounds__(256) void k_fused(const float* __restrict__ Btr,
                                               const float* __restrict__ Jx,
                                               const unsigned short* __restrict__ Abf,
                                               const float* __restrict__ na2,
                                               float* __restrict__ es_p,  // [64][NBLK_A]
                                               float* __restrict__ rs_p,
                                               __half* __restrict__ pC) { // [m][blk][216]
    __shared__ char lds[LDS_SZ];
    const int blk = blockIdx.x;
    const int t0 = blk * 32;
    const int tid = threadIdx.x;
    const int lane = tid & 63;
    const int w = __builtin_amdgcn_readfirstlane(tid >> 6);  // wave id 0..3
    const int lr = lane & 15;
    const int kb = lane >> 4;

    // A-frags hoisted to registers, L2-hot
    uint4 au[7];
    {
        const unsigned short* ap = Abf + (w * 16 + lr) * APAD + kb * 8;
#pragma unroll
        for (int k8 = 0; k8 < 7; k8++) au[k8] = *(const uint4*)(ap + k8 * 32);
    }
    if (tid < 64) *(float*)(lds + NA_OFF + tid * 4) = na2[tid];

    // ---- stage: 8-lane group per row, 32 rows; write Bs/Js row-major + X^T; fold nb/bj ----
    {
        const int g = tid >> 3, gl = tid & 7;
        int tr = t0 + g; if (tr > T_ROWS - 1) tr = T_ROWS - 1;
        const float* bp = Btr + (size_t)tr * DESC;
        const float* jp = Jx + (size_t)tr * DESC;
        float nb = 0.f, bj = 0.f;
#pragma unroll
        for (int it = 0; it < 15; it++) {
            int c = it * 8 + gl;            // 4-B granule within 464-B row
            if (c < 116) {
                float2 vb = make_float2(0.f, 0.f), vj = make_float2(0.f, 0.f);
                if (c < 105) {
                    vb = *(const float2*)(bp + 2 * c);
                    vj = *(const float2*)(jp + 2 * c);
                }
                unsigned short hbx = f2bf(vb.x), hby = f2bf(vb.y);
                unsigned short hjx = f2bf(vj.x), hjy = f2bf(vj.y);
                *(unsigned int*)(lds + BS_OFF + g * 464 + c * 4) = (unsigned)hbx | ((unsigned)hby << 16);
                *(unsigned int*)(lds + JS_OFF + g * 464 + c * 4) = (unsigned)hjx | ((unsigned)hjy << 16);
                if (c < 112) {              // X^T: d rows 2c,2c+1 ; k = g (B) / 32+g (J)
                    const int d = 2 * c;
                    *(unsigned short*)(lds + XT_OFF + d * 144 + g * 2) = hbx;
                    *(unsigned short*)(lds + XT_OFF + (d + 1) * 144 + g * 2) = hby;
                    *(unsigned short*)(lds + XT_OFF + d * 144 + 64 + g * 2) = hjx;
                    *(unsigned short*)(lds + XT_OFF + (d + 1) * 144 + 64 + g * 2) = hjy;
                }
                float fbx = bf2f(hbx), fby = bf2f(hby);
                float fjx = bf2f(hjx), fjy = bf2f(hjy);
                nb = fmaf(fbx, fbx, nb); nb = fmaf(fby, fby, nb);
                bj = fmaf(fbx, fjx, bj); bj = fmaf(fby, fjy, bj);
            }
        }
#pragma unroll
        for (int m = 1; m < 8; m <<= 1) { nb += __shfl_xor(nb, m); bj += __shfl_xor(bj, m); }
        if (gl == 0) {
            *(float*)(lds + NB_OFF + g * 4) = nb;
            *(float*)(lds + BJ_OFF + g * 4) = bj;
        }
    }
    __syncthreads();

    // ---- phase A MFMA: P = A.B^T, Q = A.J^T over K = 224, 2 t-tiles ----
    f32x4 accP[2] = {{0.f,0.f,0.f,0.f},{0.f,0.f,0.f,0.f}};
    f32x4 accQ[2] = {{0.f,0.f,0.f,0.f},{0.f,0.f,0.f,0.f}};
#pragma unroll
    for (int k8 = 0; k8 < 7; k8++) {
        union { uint4 u; bf16x8 h; } a;
        a.u = au[k8];
#pragma unroll
        for (int nt = 0; nt < 2; nt++) {
            union { uint4 u; bf16x8 h; } bu, ju;
            const int ro = (nt * 16 + lr) * 464 + k8 * 64 + kb * 16;
            bu.u = *(const uint4*)(lds + BS_OFF + ro);
            ju.u = *(const uint4*)(lds + JS_OFF + ro);
            accP[nt] = __builtin_amdgcn_mfma_f32_16x16x32_bf16(a.h, bu.h, accP[nt], 0, 0, 0);
            accQ[nt] = __builtin_amdgcn_mfma_f32_16x16x32_bf16(a.h, ju.h, accQ[nt], 0, 0, 0);
        }
    }

    // ---- epilogue: w1q/w2 -> W (bf16 LDS), es/rs -> global ----
    float na4[4];
#pragma unroll
    for (int r = 0; r < 4; r++)
        na4[r] = *(const float*)(lds + NA_OFF + (w * 16 + kb * 4 + r) * 4);
    float es4[4] = {0.f,0.f,0.f,0.f}, rs4[4] = {0.f,0.f,0.f,0.f};
#pragma unroll
    for (int nt = 0; nt < 2; nt++) {
        const int row = nt * 16 + lr;
        const float nb_c = *(const float*)(lds + NB_OFF + row * 4);
        const float bj_c = *(const float*)(lds + BJ_OFF + row * 4);
        const float msk = (t0 + row < T_ROWS) ? 1.f : 0.f;
#pragma unroll
        for (int r = 0; r < 4; r++) {
            float S = na4[r] + QCONST * QCONST * nb_c - 2.f * QCONST * accP[nt][r];
            float xd = sqrtf(fmaxf(S, 0.f));
            float e = K0CONST * __expf(-xd);
            float dot = (accQ[nt][r] - QCONST * bj_c) * msk;
            float w1 = e * dot;
            float w2 = e * (1.f + xd) * msk;   // masked: pad rows contribute nothing
            es4[r] += w2 * dot; rs4[r] += w1;
            // W[m][k]: k = t (w1q half), 32 + t (w2 half)
            const int mrow = w * 16 + kb * 4 + r;
            *(unsigned short*)(lds + W_OFF + mrow * 144 + row * 2) = f2bf(QCONST * w1);
            *(unsigned short*)(lds + W_OFF + mrow * 144 + 64 + row * 2) = f2bf(w2);
        }
    }
#pragma unroll
    for (int m = 1; m < 16; m <<= 1) {
#pragma unroll
        for (int r = 0; r < 4; r++) {
            es4[r] += __shfl_xor(es4[r], m);
            rs4[r] += __shfl_xor(rs4[r], m);
        }
    }
    if (lr == 0) {
#pragma unroll
        for (int r = 0; r < 4; r++) {
            es_p[(size_t)(w * 16 + kb * 4 + r) * NBLK_A + blk] = es4[r];
            rs_p[(size_t)(w * 16 + kb * 4 + r) * NBLK_A + blk] = rs4[r];
        }
    }
    __syncthreads();   // W/XT complete; Bs/Js no longer needed -> D_lds may alias

    // ---- phase C MFMA: D[m][d] = W . X ; wave w owns m-tile w ----
    {
        union { uint4 u; bf16x8 h; } wa0, wa1;
        const char* Wp = lds + W_OFF + (w * 16 + lr) * 144;
        wa0.u = *(const uint4*)(Wp + kb * 16);        // k = 0..31
        wa1.u = *(const uint4*)(Wp + 64 + kb * 16);   // k = 32..63
        __half* D = (__half*)lds;                     // [64][224]
#pragma unroll
        for (int dt = 0; dt < 14; dt++) {
            union { uint4 u; bf16x8 h; } xb0, xb1;
            const char* Xp = lds + XT_OFF + (dt * 16 + lr) * 144;
            xb0.u = *(const uint4*)(Xp + kb * 16);
            xb1.u = *(const uint4*)(Xp + 64 + kb * 16);
            f32x4 acc = {0.f, 0.f, 0.f, 0.f};
            acc = __builtin_amdgcn_mfma_f32_16x16x32_bf16(wa0.h, xb0.h, acc, 0, 0, 0);
            acc = __builtin_amdgcn_mfma_f32_16x16x32_bf16(wa1.h, xb1.h, acc, 0, 0, 0);
#pragma unroll
            for (int r = 0; r < 4; r++)
                D[(w * 16 + kb * 4 + r) * 224 + dt * 16 + lr] = __float2half(acc[r]);
        }
    }
    __syncthreads();

    // ---- coalesced pC store: 64 m-rows x 27 uint4 ----
    {
        const char* D = (const char*)lds;
        for (int i = tid; i < 64 * 27; i += 256) {
            const int mrow = i / 27, oct = i % 27;
            uint4 v = *(const uint4*)(D + mrow * 448 + oct * 16);
            *(uint4*)((char*)pC + (((size_t)mrow * NBLK_A + blk) * PCW + oct * 8) * 2) = v;
        }
    }
}

// ---------------- k_final: streaming c-reduction, rank-1 term, force contraction ----------------
__global__ __launch_bounds__(256) void k_final(const float* __restrict__ Rs,
                                               const unsigned short* __restrict__ Abf,
                                               const float* __restrict__ es_p,
                                               const float* __restrict__ rs_p,
                                               const __half* __restrict__ pC,
                                               float* __restrict__ out) {
    const int m = blockIdx.x;
    const int tid = threadIdx.x;
    __shared__ float parts[27][8][8];   // [octet][c-group][elem]
    __shared__ float fsx[DESC];
    __shared__ float R[N_ATOMS * 3];
    __shared__ float s_rs, s_es;
    if (tid < N_ATOMS * 3) R[tid] = Rs[m * N_ATOMS * 3 + tid];
    if (tid < 216) {   // 8 c-groups x 27 octets; fully coalesced (contiguous 3456 B / iter)
        const int cg = tid / 27, o = tid % 27;
        float facc[8];
#pragma unroll
        for (int e = 0; e < 8; e++) facc[e] = 0.f;
        const __half* base = pC + (size_t)m * NBLK_A * PCW + o * 8;
#pragma unroll 4
        for (int c = cg; c < NBLK_A; c += 8) {   // 376 = 8*47 exact
            uint4 v = *(const uint4*)(base + (size_t)c * PCW);
            const __half2* h = (const __half2*)&v;
#pragma unroll
            for (int p2 = 0; p2 < 4; p2++) {
                float2 f = __half22float2(h[p2]);
                facc[p2 * 2] += f.x;
                facc[p2 * 2 + 1] += f.y;
            }
        }
#pragma unroll
        for (int e = 0; e < 8; e++) parts[o][cg][e] = facc[e];
    }
    __syncthreads();
    if (tid < 64) {   // es/rs: contiguous 376-f32 rows
        float es = 0.f, rs = 0.f;
        for (int c2 = tid; c2 < NBLK_A; c2 += 64) {
            es += es_p[(size_t)m * NBLK_A + c2];
            rs += rs_p[(size_t)m * NBLK_A + c2];
        }
        for (int mask = 1; mask < 64; mask <<= 1) {
            es += __shfl_xor(es, mask);
            rs += __shfl_xor(rs, mask);
        }
        if (tid == 0) { s_es = es; s_rs = rs; }
    }
    __syncthreads();
    if (tid < DESC) {
        float s = 0.f;
        const int o = tid >> 3, e = tid & 7;
#pragma unroll
        for (int cg = 0; cg < 8; cg++) s += parts[o][cg][e];
        fsx[tid] = s_rs * bf2f(Abf[m * APAD + tid]) - s;  // STD = 1
    }
    if (tid == 0) out[m] = s_es * (1.0f / QCONST);        // Es = sum/q, C=0
    __syncthreads();
    if (tid < N_ATOMS * 3) {
        int b = tid / 3, kk = tid % 3;
        float acc = 0.f;
        for (int a = 0; a < N_ATOMS; a++) {
            if (a == b) continue;
            float dx = R[a * 3 + 0] - R[b * 3 + 0];
            float dy = R[a * 3 + 1] - R[b * 3 + 1];
            float dz = R[a * 3 + 2] - R[b * 3 + 2];
            float d2 = dx * dx + dy * dy + dz * dz;
            float dist = sqrtf(d2);
            float inv3 = 1.0f / (d2 * dist);
            int hi = (a > b) ? a : b, lo = (a > b) ? b : a;
            int p = hi * (hi - 1) / 2 + lo;
            float diffk = (kk == 0) ? dx : ((kk == 1) ? dy : dz);
            acc = fmaf(fsx[p] * inv3, diffk, acc);
        }
        out[BATCH + m * N_ATOMS * 3 + tid] = acc;
    }
}

extern "C" void kernel_launch(void* const* d_in, const int* in_sizes, int n_in,
                              void* d_out, int out_size, void* d_ws, size_t ws_size,
                              hipStream_t stream) {
    (void)in_sizes; (void)n_in; (void)out_size; (void)ws_size;
    const float* Rs = (const float*)d_in[0];
    const float* Btr = (const float*)d_in[1];
    const float* Jx = (const float*)d_in[2];
    float* out = (float*)d_out;

    char* ws = (char*)d_ws;
    unsigned short* Abf = (unsigned short*)ws;  ws += (size_t)BATCH * APAD * 2;   // 28.7 KB
    float* na2 = (float*)ws;                    ws += BATCH * 4;
    float* es_p = (float*)ws;                   ws += (size_t)BATCH * NBLK_A * 4; // 96 KB
    float* rs_p = (float*)ws;                   ws += (size_t)BATCH * NBLK_A * 4; // 96 KB
    __half* pC = (__half*)ws;                   // 64*376*216*2 = 10.4 MB, [m][blk][d]

    k_prep<<<dim3(BATCH), dim3(256), 0, stream>>>(Rs, Abf, na2);
    k_fused<<<dim3(NBLK_A), dim3(256), 0, stream>>>(Btr, Jx, Abf, na2, es_p, rs_p, pC);
    k_final<<<dim3(BATCH), dim3(256), 0, stream>>>(Rs, Abf, es_p, rs_p, pC, out);
}

// Round 13
// 33.317 us; speedup vs baseline: 3.2713x; 1.1051x over previous
//
#include <hip/hip_runtime.h>
#include <hip/hip_fp16.h>
#include <math.h>

#define N_ATOMS 21
#define DESC 210
#define APAD 224            // padded descriptor length (7 x 32)
#define T_ROWS 12000
#define BATCH 64
#define NBLK_A 250          // fused blocks: 48 t each, 250*48 = 12000 EXACT
#define TROWS_B 48          // t-rows per block
#define PCW 216             // pC padded row (27 x 8 halfs)

#define QCONST 0.22360679774997896f   // sqrt(5)/10
#define K0CONST (1.0f/60.0f)          // 5/(3*sig^2)

typedef short bf16x8 __attribute__((ext_vector_type(8)));
typedef float f32x4 __attribute__((ext_vector_type(4)));

__device__ __forceinline__ float u2f(unsigned int u) {
    union { unsigned int u; float f; } x; x.u = u; return x.f;
}
__device__ __forceinline__ unsigned short f2bf(float f) {
    union { float f; unsigned int u; } x; x.f = f;
    unsigned int r = x.u + 0x7fffu + ((x.u >> 16) & 1u);  // RNE
    return (unsigned short)(r >> 16);
}
__device__ __forceinline__ float bf2f(unsigned short h) {
    return u2f((unsigned int)h << 16);
}

// ---------------- k_prep: Abf[m][224] = bf16(q/dist), na2 = ||bf16 row||^2 ----------------
__global__ __launch_bounds__(256) void k_prep(const float* __restrict__ Rs,
                                              unsigned short* __restrict__ Abf,
                                              float* __restrict__ na2) {
    int m = blockIdx.x;
    __shared__ float R[N_ATOMS * 3];
    __shared__ float red[256];
    int tid = threadIdx.x;
    if (tid < N_ATOMS * 3) R[tid] = Rs[m * N_ATOMS * 3 + tid];
    __syncthreads();
    float val = 0.f;
    if (tid < DESC) {
        int p = tid;
        int i = (int)((1.0f + sqrtf(1.0f + 8.0f * (float)p)) * 0.5f);
        while (i * (i - 1) / 2 > p) --i;
        while ((i + 1) * i / 2 <= p) ++i;
        int j = p - i * (i - 1) / 2;
        float dx = R[i * 3 + 0] - R[j * 3 + 0];
        float dy = R[i * 3 + 1] - R[j * 3 + 1];
        float dz = R[i * 3 + 2] - R[j * 3 + 2];
        float d = sqrtf(dx * dx + dy * dy + dz * dz);
        val = QCONST / d;
    }
    unsigned short h = f2bf(val);
    if (tid < APAD) Abf[m * APAD + tid] = h;
    float va = bf2f(h);
    red[tid] = va * va;
    __syncthreads();
    for (int s = 128; s > 0; s >>= 1) {
        if (tid < s) red[tid] += red[tid + s];
        __syncthreads();
    }
    if (tid == 0) na2[m] = red[0];
}

// ---------------- k_fused: MFMA phase A + epilogue + MFMA phase C, 48 t/block ----------------
// 250 blocks x 256 thr (4 waves), 1 block/CU (102.6 KB LDS). No pad rows anywhere.
// Phase A: P=A.B^T, Q=A.J^T (wave = m-tile of 16, 3 t-tiles).
// Phase C: D[64m][224d] = W[64m][96k] . X[96k][224d]; K = {48 w1q|B rows, 48 w2|J rows}.
// Frag maps (R7/R8-validated): A/B row|col=lane&15, k=(lane>>4)*8+e ;
// C/D col=lane&15, row=(lane>>4)*4+r.
#define BS_OFF 0        // 48 x 464 B   (B rows, bf16, 232-wide)
#define JS_OFF 22272    // 48 x 464 B
#define XT_OFF 44544    // 224 x 208 B  (X^T: row d, 96 k-cols bf16 + pad)
#define W_OFF  91136    // 64 x 208 B   (W: row m, 96 k-cols bf16 + pad)
#define NB_OFF 104448   // 48 f32
#define BJ_OFF 104640   // 48 f32
#define NA_OFF 104832   // 64 f32
#define LDS_SZ 105088   // D_lds [64][224] half (28672 B) aliases BS/JS after phase A

__global__ __launch_bounds__(256) void k_fused(const float* __restrict__ Btr,
                                               const float* __restrict__ Jx,
                                               const unsigned short* __restrict__ Abf,
                                               const float* __restrict__ na2,
                                               float* __restrict__ es_p,  // [64][NBLK_A]
                                               float* __restrict__ rs_p,
                                               __half* __restrict__ pC) { // [m][blk][216]
    __shared__ char lds[LDS_SZ];
    const int blk = blockIdx.x;
    const int t0 = blk * TROWS_B;
    const int tid = threadIdx.x;
    const int lane = tid & 63;
    const int w = __builtin_amdgcn_readfirstlane(tid >> 6);  // wave id 0..3
    const int lr = lane & 15;
    const int kb = lane >> 4;

    // A-frags hoisted to registers, L2-hot
    uint4 au[7];
    {
        const unsigned short* ap = Abf + (w * 16 + lr) * APAD + kb * 8;
#pragma unroll
        for (int k8 = 0; k8 < 7; k8++) au[k8] = *(const uint4*)(ap + k8 * 32);
    }
    if (tid < 64) *(float*)(lds + NA_OFF + tid * 4) = na2[tid];

    // ---- stage: 8-lane group per row; rows 0..31 (all thr), rows 32..47 (waves 0-1) ----
#pragma unroll
    for (int pass = 0; pass < 2; ++pass) {
        if (pass == 1 && tid >= 128) break;   // waves 2,3 skip pass 2 (whole-wave uniform)
        const int g = pass * 32 + (tid >> 3);
        const int gl = tid & 7;
        const int tr = t0 + g;                // always < T_ROWS (250*48 = 12000 exact)
        const float* bp = Btr + (size_t)tr * DESC;
        const float* jp = Jx + (size_t)tr * DESC;
        float nb = 0.f, bj = 0.f;
#pragma unroll
        for (int it = 0; it < 15; it++) {
            int c = it * 8 + gl;              // 4-B granule within 464-B row
            if (c < 116) {
                float2 vb = make_float2(0.f, 0.f), vj = make_float2(0.f, 0.f);
                if (c < 105) {
                    vb = *(const float2*)(bp + 2 * c);
                    vj = *(const float2*)(jp + 2 * c);
                }
                unsigned short hbx = f2bf(vb.x), hby = f2bf(vb.y);
                unsigned short hjx = f2bf(vj.x), hjy = f2bf(vj.y);
                *(unsigned int*)(lds + BS_OFF + g * 464 + c * 4) = (unsigned)hbx | ((unsigned)hby << 16);
                *(unsigned int*)(lds + JS_OFF + g * 464 + c * 4) = (unsigned)hjx | ((unsigned)hjy << 16);
                if (c < 112) {                // X^T: d rows 2c,2c+1 ; k = g (B) / 48+g (J)
                    const int d = 2 * c;
                    *(unsigned short*)(lds + XT_OFF + d * 208 + g * 2) = hbx;
                    *(unsigned short*)(lds + XT_OFF + (d + 1) * 208 + g * 2) = hby;
                    *(unsigned short*)(lds + XT_OFF + d * 208 + 96 + g * 2) = hjx;
                    *(unsigned short*)(lds + XT_OFF + (d + 1) * 208 + 96 + g * 2) = hjy;
                }
                float fbx = bf2f(hbx), fby = bf2f(hby);
                float fjx = bf2f(hjx), fjy = bf2f(hjy);
                nb = fmaf(fbx, fbx, nb); nb = fmaf(fby, fby, nb);
                bj = fmaf(fbx, fjx, bj); bj = fmaf(fby, fjy, bj);
            }
        }
#pragma unroll
        for (int m = 1; m < 8; m <<= 1) { nb += __shfl_xor(nb, m); bj += __shfl_xor(bj, m); }
        if (gl == 0) {
            *(float*)(lds + NB_OFF + g * 4) = nb;
            *(float*)(lds + BJ_OFF + g * 4) = bj;
        }
    }
    __syncthreads();

    // ---- phase A MFMA: P = A.B^T, Q = A.J^T over K = 224, 3 t-tiles ----
    f32x4 accP[3] = {{0.f,0.f,0.f,0.f},{0.f,0.f,0.f,0.f},{0.f,0.f,0.f,0.f}};
    f32x4 accQ[3] = {{0.f,0.f,0.f,0.f},{0.f,0.f,0.f,0.f},{0.f,0.f,0.f,0.f}};
#pragma unroll
    for (int k8 = 0; k8 < 7; k8++) {
        union { uint4 u; bf16x8 h; } a;
        a.u = au[k8];
#pragma unroll
        for (int nt = 0; nt < 3; nt++) {
            union { uint4 u; bf16x8 h; } bu, ju;
            const int ro = (nt * 16 + lr) * 464 + k8 * 64 + kb * 16;
            bu.u = *(const uint4*)(lds + BS_OFF + ro);
            ju.u = *(const uint4*)(lds + JS_OFF + ro);
            accP[nt] = __builtin_amdgcn_mfma_f32_16x16x32_bf16(a.h, bu.h, accP[nt], 0, 0, 0);
            accQ[nt] = __builtin_amdgcn_mfma_f32_16x16x32_bf16(a.h, ju.h, accQ[nt], 0, 0, 0);
        }
    }

    // ---- epilogue: w1q/w2 -> W (bf16 LDS), es/rs -> global ----
    float na4[4];
#pragma unroll
    for (int r = 0; r < 4; r++)
        na4[r] = *(const float*)(lds + NA_OFF + (w * 16 + kb * 4 + r) * 4);
    float es4[4] = {0.f,0.f,0.f,0.f}, rs4[4] = {0.f,0.f,0.f,0.f};
#pragma unroll
    for (int nt = 0; nt < 3; nt++) {
        const int row = nt * 16 + lr;
        const float nb_c = *(const float*)(lds + NB_OFF + row * 4);
        const float bj_c = *(const float*)(lds + BJ_OFF + row * 4);
#pragma unroll
        for (int r = 0; r < 4; r++) {
            float S = na4[r] + QCONST * QCONST * nb_c - 2.f * QCONST * accP[nt][r];
            float xd = sqrtf(fmaxf(S, 0.f));
            float e = K0CONST * __expf(-xd);
            float dot = accQ[nt][r] - QCONST * bj_c;
            float w1 = e * dot;
            float w2 = e * (1.f + xd);
            es4[r] += w2 * dot; rs4[r] += w1;
            // W[m][k]: k = row (w1q half), 48 + row (w2 half)
            const int mrow = w * 16 + kb * 4 + r;
            *(unsigned short*)(lds + W_OFF + mrow * 208 + row * 2) = f2bf(QCONST * w1);
            *(unsigned short*)(lds + W_OFF + mrow * 208 + 96 + row * 2) = f2bf(w2);
        }
    }
#pragma unroll
    for (int m = 1; m < 16; m <<= 1) {
#pragma unroll
        for (int r = 0; r < 4; r++) {
            es4[r] += __shfl_xor(es4[r], m);
            rs4[r] += __shfl_xor(rs4[r], m);
        }
    }
    if (lr == 0) {
#pragma unroll
        for (int r = 0; r < 4; r++) {
            es_p[(size_t)(w * 16 + kb * 4 + r) * NBLK_A + blk] = es4[r];
            rs_p[(size_t)(w * 16 + kb * 4 + r) * NBLK_A + blk] = rs4[r];
        }
    }
    __syncthreads();   // W/XT complete; Bs/Js dead -> D_lds may alias

    // ---- phase C MFMA: D[m][d] = W . X over K = 96; wave w owns m-tile w ----
    {
        union { uint4 u; bf16x8 h; } wa[3];
        const char* Wp = lds + W_OFF + (w * 16 + lr) * 208;
#pragma unroll
        for (int c = 0; c < 3; c++) wa[c].u = *(const uint4*)(Wp + c * 64 + kb * 16);
        __half* D = (__half*)lds;                     // [64][224]
#pragma unroll
        for (int dt = 0; dt < 14; dt++) {
            const char* Xp = lds + XT_OFF + (dt * 16 + lr) * 208;
            f32x4 acc = {0.f, 0.f, 0.f, 0.f};
#pragma unroll
            for (int c = 0; c < 3; c++) {
                union { uint4 u; bf16x8 h; } xb;
                xb.u = *(const uint4*)(Xp + c * 64 + kb * 16);
                acc = __builtin_amdgcn_mfma_f32_16x16x32_bf16(wa[c].h, xb.h, acc, 0, 0, 0);
            }
#pragma unroll
            for (int r = 0; r < 4; r++)
                D[(w * 16 + kb * 4 + r) * 224 + dt * 16 + lr] = __float2half(acc[r]);
        }
    }
    __syncthreads();

    // ---- coalesced pC store: 64 m-rows x 27 uint4 ----
    {
        const char* D = (const char*)lds;
        for (int i = tid; i < 64 * 27; i += 256) {
            const int mrow = i / 27, oct = i % 27;
            uint4 v = *(const uint4*)(D + mrow * 448 + oct * 16);
            *(uint4*)((char*)pC + (((size_t)mrow * NBLK_A + blk) * PCW + oct * 8) * 2) = v;
        }
    }
}

// ---------------- k_final: streaming c-reduction, rank-1 term, force contraction ----------------
__global__ __launch_bounds__(256) void k_final(const float* __restrict__ Rs,
                                               const unsigned short* __restrict__ Abf,
                                               const float* __restrict__ es_p,
                                               const float* __restrict__ rs_p,
                                               const __half* __restrict__ pC,
                                               float* __restrict__ out) {
    const int m = blockIdx.x;
    const int tid = threadIdx.x;
    __shared__ float parts[27][8][8];   // [octet][c-group][elem]
    __shared__ float fsx[DESC];
    __shared__ float R[N_ATOMS * 3];
    __shared__ float s_rs, s_es;
    if (tid < N_ATOMS * 3) R[tid] = Rs[m * N_ATOMS * 3 + tid];
    if (tid < 216) {   // 8 c-groups x 27 octets; fully coalesced
        const int cg = tid / 27, o = tid % 27;
        float facc[8];
#pragma unroll
        for (int e = 0; e < 8; e++) facc[e] = 0.f;
        const __half* base = pC + (size_t)m * NBLK_A * PCW + o * 8;
#pragma unroll 4
        for (int c = cg; c < NBLK_A; c += 8) {
            uint4 v = *(const uint4*)(base + (size_t)c * PCW);
            const __half2* h = (const __half2*)&v;
#pragma unroll
            for (int p2 = 0; p2 < 4; p2++) {
                float2 f = __half22float2(h[p2]);
                facc[p2 * 2] += f.x;
                facc[p2 * 2 + 1] += f.y;
            }
        }
#pragma unroll
        for (int e = 0; e < 8; e++) parts[o][cg][e] = facc[e];
    }
    __syncthreads();
    if (tid < 64) {   // es/rs: contiguous 250-f32 rows
        float es = 0.f, rs = 0.f;
        for (int c2 = tid; c2 < NBLK_A; c2 += 64) {
            es += es_p[(size_t)m * NBLK_A + c2];
            rs += rs_p[(size_t)m * NBLK_A + c2];
        }
        for (int mask = 1; mask < 64; mask <<= 1) {
            es += __shfl_xor(es, mask);
            rs += __shfl_xor(rs, mask);
        }
        if (tid == 0) { s_es = es; s_rs = rs; }
    }
    __syncthreads();
    if (tid < DESC) {
        float s = 0.f;
        const int o = tid >> 3, e = tid & 7;
#pragma unroll
        for (int cg = 0; cg < 8; cg++) s += parts[o][cg][e];
        fsx[tid] = s_rs * bf2f(Abf[m * APAD + tid]) - s;  // STD = 1
    }
    if (tid == 0) out[m] = s_es * (1.0f / QCONST);        // Es = sum/q, C=0
    __syncthreads();
    if (tid < N_ATOMS * 3) {
        int b = tid / 3, kk = tid % 3;
        float acc = 0.f;
        for (int a = 0; a < N_ATOMS; a++) {
            if (a == b) continue;
            float dx = R[a * 3 + 0] - R[b * 3 + 0];
            float dy = R[a * 3 + 1] - R[b * 3 + 1];
            float dz = R[a * 3 + 2] - R[b * 3 + 2];
            float d2 = dx * dx + dy * dy + dz * dz;
            float dist = sqrtf(d2);
            float inv3 = 1.0f / (d2 * dist);
            int hi = (a > b) ? a : b, lo = (a > b) ? b : a;
            int p = hi * (hi - 1) / 2 + lo;
            float diffk = (kk == 0) ? dx : ((kk == 1) ? dy : dz);
            acc = fmaf(fsx[p] * inv3, diffk, acc);
        }
        out[BATCH + m * N_ATOMS * 3 + tid] = acc;
    }
}

extern "C" void kernel_launch(void* const* d_in, const int* in_sizes, int n_in,
                              void* d_out, int out_size, void* d_ws, size_t ws_size,
                              hipStream_t stream) {
    (void)in_sizes; (void)n_in; (void)out_size; (void)ws_size;
    const float* Rs = (const float*)d_in[0];
    const float* Btr = (const float*)d_in[1];
    const float* Jx = (const float*)d_in[2];
    float* out = (float*)d_out;

    char* ws = (char*)d_ws;
    unsigned short* Abf = (unsigned short*)ws;  ws += (size_t)BATCH * APAD * 2;   // 28.7 KB
    float* na2 = (float*)ws;                    ws += BATCH * 4;
    float* es_p = (float*)ws;                   ws += (size_t)BATCH * NBLK_A * 4; // 64 KB
    float* rs_p = (float*)ws;                   ws += (size_t)BATCH * NBLK_A * 4; // 64 KB
    __half* pC = (__half*)ws;                   // 64*250*216*2 = 6.9 MB, [m][blk][d]

    k_prep<<<dim3(BATCH), dim3(256), 0, stream>>>(Rs, Abf, na2);
    k_fused<<<dim3(NBLK_A), dim3(256), 0, stream>>>(Btr, Jx, Abf, na2, es_p, rs_p, pC);
    k_final<<<dim3(BATCH), dim3(256), 0, stream>>>(Rs, Abf, es_p, rs_p, pC, out);
}